// Round 9
// baseline (382.132 us; speedup 1.0000x reference)
//
#include <hip/hip_runtime.h>
#include <hip/hip_bf16.h>

#define NN 50000
#define NE 800000
#define DD 128
#define NB 196             // ceil(NN/256)
#define NCH 8              // source chunks (1.6 MB bf16 slice each)
#define CHSZ 6250          // NN / NCH
#define NC2 (NN * NCH)     // per-(node,chunk) bins = 400000
#define NSB 391            // ceil(NC2/1024)
#define PH (64 * NB)       // degree-bucket histogram size = 12544
#define FS 2048            // fill: edges per slice
#define NSL 391            // ceil(NE/FS)
#define HB 3125            // hist blocks (NE/256)
#define CB 3125            // cast blocks (NN*DD/8/256)
#define WB 192             // wtcast blocks
#define SLICE_BYTES 1600000  // CHSZ * DD * 2
#define SLICE_LINES 25600    // SLICE_BYTES / 64
#define LN_EPS 1e-5f

typedef __bf16 bf16x8 __attribute__((ext_vector_type(8)));
typedef float f32x4 __attribute__((ext_vector_type(4)));

__device__ inline ushort f2bf_bits(float f) {
    union { __hip_bfloat16 h; ushort u; } c;
    c.h = __float2bfloat16(f);
    return c.u;
}

// ---------------- fused: per-(dst,chunk) histogram + feature cast + Wt cast ----------------
__global__ void hist_cast_kernel(const int* __restrict__ src, const int* __restrict__ dst,
                                 int* __restrict__ counts2, const float* __restrict__ x,
                                 uint4* __restrict__ fb0, const float* __restrict__ W,
                                 ushort* __restrict__ Wt) {
    int b = blockIdx.x;
    if (b < HB) {
        int e = b * 256 + threadIdx.x;
        int s = src[e], d = dst[e];
        atomicAdd(&counts2[d * NCH + s / CHSZ], 1);
    } else if (b < HB + CB) {
        int i = (b - HB) * 256 + threadIdx.x;  // 800000 threads x 8 floats
        float4 v0 = ((const float4*)x)[2 * i];
        float4 v1 = ((const float4*)x)[2 * i + 1];
        union { ushort us[8]; uint4 u; } pk;
        pk.us[0] = f2bf_bits(v0.x); pk.us[1] = f2bf_bits(v0.y);
        pk.us[2] = f2bf_bits(v0.z); pk.us[3] = f2bf_bits(v0.w);
        pk.us[4] = f2bf_bits(v1.x); pk.us[5] = f2bf_bits(v1.y);
        pk.us[6] = f2bf_bits(v1.z); pk.us[7] = f2bf_bits(v1.w);
        fb0[i] = pk.u;
    } else {
        int i = (b - HB - CB) * 256 + threadIdx.x;  // 3*128*128 = 49152
        int l = i >> 14, k = (i >> 7) & 127, n = i & 127;
        Wt[l * 16384 + n * 128 + k] = f2bf_bits(W[i]);
    }
}

// level-0 scan over NC2 elements, 1024 threads/block, in-place; emits block sums
__global__ __launch_bounds__(1024) void scan1024_blocks(int* __restrict__ data,
                                                        int* __restrict__ bsums) {
    __shared__ int ws[16];
    int gid = blockIdx.x * 1024 + threadIdx.x;
    int lane = threadIdx.x & 63, wid = threadIdx.x >> 6;
    int v = (gid < NC2) ? data[gid] : 0;
    int x = v;
#pragma unroll
    for (int off = 1; off < 64; off <<= 1) {
        int t = __shfl_up(x, off, 64);
        if (lane >= off) x += t;
    }
    if (lane == 63) ws[wid] = x;
    __syncthreads();
    if (threadIdx.x == 0) {
        int run = 0;
        for (int i = 0; i < 16; ++i) { int t = ws[i]; ws[i] = run; run += t; }
        bsums[blockIdx.x] = run;
    }
    __syncthreads();
    if (gid < NC2) data[gid] = x - v + ws[wid];
}

// level-1: single block scans the 391 block sums
__global__ __launch_bounds__(1024) void scan_sums1024(int* __restrict__ bsums, int nb) {
    __shared__ int ws[16];
    int tid = threadIdx.x;
    int lane = tid & 63, wid = tid >> 6;
    int v = (tid < nb) ? bsums[tid] : 0;
    int x = v;
#pragma unroll
    for (int off = 1; off < 64; off <<= 1) {
        int t = __shfl_up(x, off, 64);
        if (lane >= off) x += t;
    }
    if (lane == 63) ws[wid] = x;
    __syncthreads();
    if (tid == 0) {
        int run = 0;
        for (int i = 0; i < 16; ++i) { int t = ws[i]; ws[i] = run; run += t; }
    }
    __syncthreads();
    if (tid < nb) bsums[tid] = x - v + ws[wid];
}

// absolute cursors (+ persistent rp2 copy), row_ptr, degree, dinv + degree histogram
__global__ void finalize_kernel(const int* __restrict__ excl2, const int* __restrict__ bsums,
                                int* __restrict__ row_ptr, int* __restrict__ next_pos2,
                                int* __restrict__ rp2, float* __restrict__ dinv,
                                int* __restrict__ degarr, int* __restrict__ bh) {
    __shared__ int lh[64];
    if (threadIdx.x < 64) lh[threadIdx.x] = 0;
    __syncthreads();
    int d = blockIdx.x * 256 + threadIdx.x;
    if (d < NN) {
        int base = d * NCH;
        int p0 = excl2[base] + bsums[base >> 10];
#pragma unroll
        for (int c = 0; c < NCH; ++c) {
            int idx = base + c;
            int v = excl2[idx] + bsums[idx >> 10];
            next_pos2[idx] = v;
            rp2[idx] = v;
        }
        int nxt = (d == NN - 1) ? NE : excl2[base + NCH] + bsums[(base + NCH) >> 10];
        int deg = nxt - p0;
        row_ptr[d] = p0;
        dinv[d] = rsqrtf((float)deg + 1.0f);
        degarr[d] = deg;
        atomicAdd(&lh[min(deg, 63)], 1);
    }
    __syncthreads();
    if (threadIdx.x < 64) bh[threadIdx.x * NB + blockIdx.x] = lh[threadIdx.x];
    if (blockIdx.x == 0 && threadIdx.x == 0) row_ptr[NN] = NE;
}

__global__ __launch_bounds__(1024) void permscan_kernel(int* __restrict__ bh) {
    __shared__ int wsum[16];
    const int CH = 13;  // 1024*13 = 13312 >= 12544
    int tid = threadIdx.x;
    int base = tid * CH;
    int vals[CH];
    int s = 0;
#pragma unroll
    for (int i = 0; i < CH; ++i) {
        int idx = base + i;
        int v = (idx < PH) ? bh[idx] : 0;
        vals[i] = s;
        s += v;
    }
    int lane = tid & 63, wid = tid >> 6;
    int x = s;
#pragma unroll
    for (int off = 1; off < 64; off <<= 1) {
        int t = __shfl_up(x, off, 64);
        if (lane >= off) x += t;
    }
    if (lane == 63) wsum[wid] = x;
    __syncthreads();
    if (tid == 0) {
        int run = 0;
        for (int i = 0; i < 16; ++i) { int t = wsum[i]; wsum[i] = run; run += t; }
    }
    __syncthreads();
    int texcl = x - s + wsum[wid];
#pragma unroll
    for (int i = 0; i < CH; ++i) {
        int idx = base + i;
        if (idx < PH) bh[idx] = texcl + vals[i];
    }
}

__global__ void permscatter_kernel(const int* __restrict__ degarr, const int* __restrict__ bh,
                                   int* __restrict__ perm) {
    __shared__ int lh[64];
    __shared__ int lbase[64];
    if (threadIdx.x < 64) {
        lh[threadIdx.x] = 0;
        lbase[threadIdx.x] = bh[threadIdx.x * NB + blockIdx.x];
    }
    __syncthreads();
    int gid = blockIdx.x * 256 + threadIdx.x;
    if (gid < NN) {
        int b = min(degarr[gid], 63);
        int r = atomicAdd(&lh[b], 1);
        perm[lbase[b] + r] = gid;
    }
}

// XCD-partitioned fill: block b scans edge slice (b>>3), handles only dst range (b&7).
__global__ void fill_kernel(const int* __restrict__ src, const int* __restrict__ dst,
                            int* __restrict__ next_pos2, const float* __restrict__ dinv,
                            int2* __restrict__ edge2) {
    int slice = blockIdx.x >> 3;
    int r = blockIdx.x & 7;
    int base = slice * FS;
#pragma unroll 2
    for (int i = threadIdx.x; i < FS; i += 256) {
        int e = base + i;
        if (e < NE) {
            int d = dst[e];
            if (d / CHSZ == r) {
                int s = src[e];
                int pos = atomicAdd(&next_pos2[d * NCH + s / CHSZ], 1);
                int2 o;
                o.x = s;
                o.y = __float_as_int(dinv[s] * dinv[d]);
                edge2[pos] = o;
            }
        }
    }
}

// ---------------- fused per-layer: chunk-phased gather + prefetch + MFMA + LN ----------------
// Gather processes each node's edges in 8 chunk phases (same order as before -> identical
// numerics). Per phase, threads 0..67 stream-touch every 64B line of the NEXT slice so the
// per-XCD L2 is refilled in sequential order (R8 evidence: random 64B demand refill caps at
// ~2.7 TB/s vs ~6.3 TB/s sequential).
template <bool RES, bool FINAL>
__global__ __launch_bounds__(256) void layer_kernel(
    const ushort* __restrict__ fin, const int* __restrict__ row_ptr,
    const int* __restrict__ rp2, const int2* __restrict__ edge2,
    const int* __restrict__ perm, const float* __restrict__ dinv,
    const ushort* __restrict__ Wt, const float* __restrict__ bias,
    const float* __restrict__ gamma, const float* __restrict__ beta,
    ushort* __restrict__ fout, float* __restrict__ out, int* __restrict__ scratch) {
    __shared__ uint4 sA[16 * 17];
    __shared__ int sNode[16];
    __shared__ float sLN1[4][16], sLN2[4][16];

    int w = threadIdx.x >> 6, lane = threadIdx.x & 63;
    int g = lane >> 4, t = lane & 15;
    int arow = w * 4 + g;
    int slot = blockIdx.x * 16 + arow;  // grid 3125*16 = 50000 exact
    int node = perm[slot];
    if (t == 0) sNode[arow] = node;

    const char* fc = (const char*)fin;
    int pfline = (blockIdx.x >> 3) * 68 + threadIdx.x;  // line index within a slice
    bool dopf = (threadIdx.x < 68) && (pfline < SLICE_LINES);
    uint pfs = 0;
    if (dopf) pfs ^= *(const uint*)(fc + (size_t)pfline * 64);  // warm slice 0

    // ---- phase 1: chunk-phased gather-aggregate (16 lanes x 16B per node row) ----
    int base2 = node * NCH;
    int endrow = row_ptr[node + 1];
    const uint4* cu4 = (const uint4*)fin;
    float acc[8] = {};
#pragma unroll 1
    for (int c = 0; c < NCH; ++c) {
        uint va = 0;
        if (c + 1 < NCH && dopf)
            va = *(const uint*)(fc + (size_t)(c + 1) * SLICE_BYTES + (size_t)pfline * 64);
        int e = rp2[base2 + c];
        int segend = (c + 1 < NCH) ? rp2[base2 + c + 1] : endrow;
        for (; e + 2 <= segend; e += 2) {
            int2 a0 = edge2[e + 0];
            int2 a1 = edge2[e + 1];
            uint4 v0 = cu4[a0.x * 16 + t];
            uint4 v1 = cu4[a1.x * 16 + t];
            uint vv0[4] = {v0.x, v0.y, v0.z, v0.w};
            uint vv1[4] = {v1.x, v1.y, v1.z, v1.w};
            float w0 = __int_as_float(a0.y), w1 = __int_as_float(a1.y);
#pragma unroll
            for (int i = 0; i < 4; ++i) {
                acc[2 * i] = fmaf(w0, __uint_as_float(vv0[i] << 16), acc[2 * i]);
                acc[2 * i + 1] = fmaf(w0, __uint_as_float(vv0[i] & 0xffff0000u), acc[2 * i + 1]);
                acc[2 * i] = fmaf(w1, __uint_as_float(vv1[i] << 16), acc[2 * i]);
                acc[2 * i + 1] = fmaf(w1, __uint_as_float(vv1[i] & 0xffff0000u), acc[2 * i + 1]);
            }
        }
        if (e < segend) {
            int2 a = edge2[e];
            uint4 v = cu4[a.x * 16 + t];
            uint vv[4] = {v.x, v.y, v.z, v.w};
            float ww = __int_as_float(a.y);
#pragma unroll
            for (int i = 0; i < 4; ++i) {
                acc[2 * i] = fmaf(ww, __uint_as_float(vv[i] << 16), acc[2 * i]);
                acc[2 * i + 1] = fmaf(ww, __uint_as_float(vv[i] & 0xffff0000u), acc[2 * i + 1]);
            }
        }
        pfs ^= va;
        __syncthreads();  // phase-lock the block's waves on the chunk sweep
    }
    {
        float di = dinv[node];
        float w2s = di * di;
        uint4 v = cu4[node * 16 + t];
        uint vv[4] = {v.x, v.y, v.z, v.w};
#pragma unroll
        for (int i = 0; i < 4; ++i) {
            acc[2 * i] = fmaf(w2s, __uint_as_float(vv[i] << 16), acc[2 * i]);
            acc[2 * i + 1] = fmaf(w2s, __uint_as_float(vv[i] & 0xffff0000u), acc[2 * i + 1]);
        }
        union { ushort us[8]; uint4 u; } pk;
#pragma unroll
        for (int i = 0; i < 8; ++i) pk.us[i] = f2bf_bits(acc[i]);
        sA[arow * 17 + t] = pk.u;
    }
    __syncthreads();

    // ---- phase 2: MFMA 16x128 tile; wave w owns col-tiles 2w, 2w+1 ----
    int q = lane >> 4, m = lane & 15;
    f32x4 c0 = (f32x4){0.f, 0.f, 0.f, 0.f};
    f32x4 c1 = (f32x4){0.f, 0.f, 0.f, 0.f};
    int n0 = 16 * (2 * w), n1 = 16 * (2 * w + 1);
#pragma unroll
    for (int kk = 0; kk < 4; ++kk) {
        bf16x8 af = *(const bf16x8*)&sA[m * 17 + kk * 4 + q];
        bf16x8 b0 = *(const bf16x8*)(Wt + (n0 + m) * DD + kk * 32 + q * 8);
        bf16x8 b1 = *(const bf16x8*)(Wt + (n1 + m) * DD + kk * 32 + q * 8);
        c0 = __builtin_amdgcn_mfma_f32_16x16x32_bf16(af, b0, c0, 0, 0, 0);
        c1 = __builtin_amdgcn_mfma_f32_16x16x32_bf16(af, b1, c1, 0, 0, 0);
    }

    // ---- epilogue: bias + LN (in-wave m-reduce, LDS cross-wave combine) + ReLU + res ----
    float bb0 = bias[n0 + m], bb1 = bias[n1 + m];
    float s1[4], s2[4];
#pragma unroll
    for (int r = 0; r < 4; ++r) {
        float v0 = c0[r] + bb0, v1 = c1[r] + bb1;
        c0[r] = v0; c1[r] = v1;
        s1[r] = v0 + v1;
        s2[r] = v0 * v0 + v1 * v1;
    }
#pragma unroll
    for (int off = 1; off <= 8; off <<= 1) {
#pragma unroll
        for (int r = 0; r < 4; ++r) {
            s1[r] += __shfl_xor(s1[r], off, 64);
            s2[r] += __shfl_xor(s2[r], off, 64);
        }
    }
    if (m == 0) {
#pragma unroll
        for (int r = 0; r < 4; ++r) {
            sLN1[w][q * 4 + r] = s1[r];
            sLN2[w][q * 4 + r] = s2[r];
        }
    }
    __syncthreads();
    float ga0 = gamma[n0 + m], ga1 = gamma[n1 + m];
    float be0 = beta[n0 + m], be1 = beta[n1 + m];
#pragma unroll
    for (int r = 0; r < 4; ++r) {
        int row = q * 4 + r;
        float S1 = sLN1[0][row] + sLN1[1][row] + sLN1[2][row] + sLN1[3][row];
        float S2 = sLN2[0][row] + sLN2[1][row] + sLN2[2][row] + sLN2[3][row];
        float mu = S1 * (1.f / 128.f);
        float var = S2 * (1.f / 128.f) - mu * mu;
        float rstd = rsqrtf(var + LN_EPS);
        int nd = sNode[row];
        size_t rb = (size_t)nd * DD;
        float o0 = fmaxf((c0[r] - mu) * rstd * ga0 + be0, 0.f);
        float o1 = fmaxf((c1[r] - mu) * rstd * ga1 + be1, 0.f);
        if (RES) {
            o0 += __uint_as_float(((uint)fin[rb + n0 + m]) << 16);
            o1 += __uint_as_float(((uint)fin[rb + n1 + m]) << 16);
        }
        if (FINAL) {
            out[rb + n0 + m] = o0;
            out[rb + n1 + m] = o1;
        } else {
            fout[rb + n0 + m] = f2bf_bits(o0);
            fout[rb + n1 + m] = f2bf_bits(o1);
        }
    }
    if (pfs == 0xDEADBEEFu) *scratch = (int)pfs;  // data-dependent sink keeps prefetch alive
}

// ---------------- launch ----------------

extern "C" void kernel_launch(void* const* d_in, const int* in_sizes, int n_in,
                              void* d_out, int out_size, void* d_ws, size_t ws_size,
                              hipStream_t stream) {
    const float* x = (const float*)d_in[0];
    const int* edge = (const int*)d_in[1];
    const float* Ws = (const float*)d_in[2];
    const float* bs = (const float*)d_in[3];
    const float* gs = (const float*)d_in[4];
    const float* bes = (const float*)d_in[5];
    float* out = (float*)d_out;
    const int* src = edge;
    const int* dst = edge + NE;

    char* p = (char*)d_ws;
    int* counts2 = (int*)p;     p += (size_t)NC2 * 4;     // scanned in place
    int* bsums = (int*)p;       p += 1024 * 4;
    int* row_ptr = (int*)p;     p += (size_t)(NN + 4) * 4;
    int* next_pos2 = (int*)p;   p += (size_t)NC2 * 4;
    int* rp2 = (int*)p;         p += (size_t)NC2 * 4;
    float* dinv = (float*)p;    p += (size_t)NN * 4;
    int* degarr = (int*)p;      p += (size_t)NN * 4;
    int* bh = (int*)p;          p += (size_t)PH * 4;
    int* perm = (int*)p;        p += (size_t)NN * 4;
    int2* edge2 = (int2*)p;     p += (size_t)NE * 8;
    ushort* fb0 = (ushort*)p;   p += (size_t)NN * DD * 2;
    ushort* fb1 = (ushort*)p;   p += (size_t)NN * DD * 2;
    ushort* Wt = (ushort*)p;    p += (size_t)3 * DD * DD * 2;
    int* scratch = bsums + 512;  // unused tail of bsums block

    hipMemsetAsync(counts2, 0, (size_t)NC2 * 4, stream);
    hist_cast_kernel<<<HB + CB + WB, 256, 0, stream>>>(src, dst, counts2, x, (uint4*)fb0, Ws,
                                                       Wt);
    scan1024_blocks<<<NSB, 1024, 0, stream>>>(counts2, bsums);
    scan_sums1024<<<1, 1024, 0, stream>>>(bsums, NSB);
    finalize_kernel<<<NB, 256, 0, stream>>>(counts2, bsums, row_ptr, next_pos2, rp2, dinv,
                                            degarr, bh);
    permscan_kernel<<<1, 1024, 0, stream>>>(bh);
    permscatter_kernel<<<NB, 256, 0, stream>>>(degarr, bh, perm);
    fill_kernel<<<NSL * 8, 256, 0, stream>>>(src, dst, next_pos2, dinv, edge2);

    int lg = NN / 16;  // 3125
    layer_kernel<false, false><<<lg, 256, 0, stream>>>(
        fb0, row_ptr, rp2, edge2, perm, dinv, Wt, bs, gs, bes, fb1, out, scratch);
    layer_kernel<true, false><<<lg, 256, 0, stream>>>(
        fb1, row_ptr, rp2, edge2, perm, dinv, Wt + 16384, bs + DD, gs + DD, bes + DD, fb0, out,
        scratch);
    layer_kernel<true, true><<<lg, 256, 0, stream>>>(
        fb0, row_ptr, rp2, edge2, perm, dinv, Wt + 32768, bs + 2 * DD, gs + 2 * DD,
        bes + 2 * DD, fb1, out, scratch);
}

// Round 10
// 331.624 us; speedup vs baseline: 1.1523x; 1.1523x over previous
//
#include <hip/hip_runtime.h>
#include <hip/hip_bf16.h>

#define NN 50000
#define NE 800000
#define DD 128
#define NB 196             // ceil(NN/256)
#define NCH 8              // source chunks (1.6 MB bf16 slice each)
#define CHSZ 6250          // NN / NCH
#define NC2 (NN * NCH)     // per-(node,chunk) bins = 400000
#define NSB 391            // ceil(NC2/1024)
#define PH (64 * NB)       // degree-bucket histogram size = 12544
#define FS 2048            // fill: edges per slice
#define NSL 391            // ceil(NE/FS)
#define HB 3125            // hist blocks (NE/256)
#define CB 3125            // cast blocks (NN*DD/8/256)
#define WB 192             // wtcast blocks
#define LN_EPS 1e-5f

typedef __bf16 bf16x8 __attribute__((ext_vector_type(8)));
typedef float f32x4 __attribute__((ext_vector_type(4)));

__device__ inline ushort f2bf_bits(float f) {
    union { __hip_bfloat16 h; ushort u; } c;
    c.h = __float2bfloat16(f);
    return c.u;
}

// ---------------- fused: per-(dst,chunk) histogram + feature cast + Wt cast ----------------
__global__ void hist_cast_kernel(const int* __restrict__ src, const int* __restrict__ dst,
                                 int* __restrict__ counts2, const float* __restrict__ x,
                                 uint4* __restrict__ fb0, const float* __restrict__ W,
                                 ushort* __restrict__ Wt) {
    int b = blockIdx.x;
    if (b < HB) {
        int e = b * 256 + threadIdx.x;
        int s = src[e], d = dst[e];
        atomicAdd(&counts2[d * NCH + s / CHSZ], 1);
    } else if (b < HB + CB) {
        int i = (b - HB) * 256 + threadIdx.x;  // 800000 threads x 8 floats
        float4 v0 = ((const float4*)x)[2 * i];
        float4 v1 = ((const float4*)x)[2 * i + 1];
        union { ushort us[8]; uint4 u; } pk;
        pk.us[0] = f2bf_bits(v0.x); pk.us[1] = f2bf_bits(v0.y);
        pk.us[2] = f2bf_bits(v0.z); pk.us[3] = f2bf_bits(v0.w);
        pk.us[4] = f2bf_bits(v1.x); pk.us[5] = f2bf_bits(v1.y);
        pk.us[6] = f2bf_bits(v1.z); pk.us[7] = f2bf_bits(v1.w);
        fb0[i] = pk.u;
    } else {
        int i = (b - HB - CB) * 256 + threadIdx.x;  // 3*128*128 = 49152
        int l = i >> 14, k = (i >> 7) & 127, n = i & 127;
        Wt[l * 16384 + n * 128 + k] = f2bf_bits(W[i]);
    }
}

// level-0 scan over NC2 elements, 1024 threads/block, in-place; emits block sums
__global__ __launch_bounds__(1024) void scan1024_blocks(int* __restrict__ data,
                                                        int* __restrict__ bsums) {
    __shared__ int ws[16];
    int gid = blockIdx.x * 1024 + threadIdx.x;
    int lane = threadIdx.x & 63, wid = threadIdx.x >> 6;
    int v = (gid < NC2) ? data[gid] : 0;
    int x = v;
#pragma unroll
    for (int off = 1; off < 64; off <<= 1) {
        int t = __shfl_up(x, off, 64);
        if (lane >= off) x += t;
    }
    if (lane == 63) ws[wid] = x;
    __syncthreads();
    if (threadIdx.x == 0) {
        int run = 0;
        for (int i = 0; i < 16; ++i) { int t = ws[i]; ws[i] = run; run += t; }
        bsums[blockIdx.x] = run;
    }
    __syncthreads();
    if (gid < NC2) data[gid] = x - v + ws[wid];
}

// level-1: single block scans the 391 block sums
__global__ __launch_bounds__(1024) void scan_sums1024(int* __restrict__ bsums, int nb) {
    __shared__ int ws[16];
    int tid = threadIdx.x;
    int lane = tid & 63, wid = tid >> 6;
    int v = (tid < nb) ? bsums[tid] : 0;
    int x = v;
#pragma unroll
    for (int off = 1; off < 64; off <<= 1) {
        int t = __shfl_up(x, off, 64);
        if (lane >= off) x += t;
    }
    if (lane == 63) ws[wid] = x;
    __syncthreads();
    if (tid == 0) {
        int run = 0;
        for (int i = 0; i < 16; ++i) { int t = ws[i]; ws[i] = run; run += t; }
    }
    __syncthreads();
    if (tid < nb) bsums[tid] = x - v + ws[wid];
}

// absolute cursors, row_ptr, degree, dinv + fused per-block degree histogram
__global__ void finalize_kernel(const int* __restrict__ excl2, const int* __restrict__ bsums,
                                int* __restrict__ row_ptr, int* __restrict__ next_pos2,
                                float* __restrict__ dinv, int* __restrict__ degarr,
                                int* __restrict__ bh) {
    __shared__ int lh[64];
    if (threadIdx.x < 64) lh[threadIdx.x] = 0;
    __syncthreads();
    int d = blockIdx.x * 256 + threadIdx.x;
    if (d < NN) {
        int base = d * NCH;
        int p0 = excl2[base] + bsums[base >> 10];
#pragma unroll
        for (int c = 0; c < NCH; ++c) {
            int idx = base + c;
            next_pos2[idx] = excl2[idx] + bsums[idx >> 10];
        }
        int nxt = (d == NN - 1) ? NE : excl2[base + NCH] + bsums[(base + NCH) >> 10];
        int deg = nxt - p0;
        row_ptr[d] = p0;
        dinv[d] = rsqrtf((float)deg + 1.0f);
        degarr[d] = deg;
        atomicAdd(&lh[min(deg, 63)], 1);
    }
    __syncthreads();
    if (threadIdx.x < 64) bh[threadIdx.x * NB + blockIdx.x] = lh[threadIdx.x];
    if (blockIdx.x == 0 && threadIdx.x == 0) row_ptr[NN] = NE;
}

__global__ __launch_bounds__(1024) void permscan_kernel(int* __restrict__ bh) {
    __shared__ int wsum[16];
    const int CH = 13;  // 1024*13 = 13312 >= 12544
    int tid = threadIdx.x;
    int base = tid * CH;
    int vals[CH];
    int s = 0;
#pragma unroll
    for (int i = 0; i < CH; ++i) {
        int idx = base + i;
        int v = (idx < PH) ? bh[idx] : 0;
        vals[i] = s;
        s += v;
    }
    int lane = tid & 63, wid = tid >> 6;
    int x = s;
#pragma unroll
    for (int off = 1; off < 64; off <<= 1) {
        int t = __shfl_up(x, off, 64);
        if (lane >= off) x += t;
    }
    if (lane == 63) wsum[wid] = x;
    __syncthreads();
    if (tid == 0) {
        int run = 0;
        for (int i = 0; i < 16; ++i) { int t = wsum[i]; wsum[i] = run; run += t; }
    }
    __syncthreads();
    int texcl = x - s + wsum[wid];
#pragma unroll
    for (int i = 0; i < CH; ++i) {
        int idx = base + i;
        if (idx < PH) bh[idx] = texcl + vals[i];
    }
}

// merged: blocks [0,NB) = degree-bucket permscatter; blocks [NB, NB+NSL*8) = XCD-
// partitioned fill (block b scans edge slice ((b-NB)>>3), handles dst range ((b-NB)&7)).
__global__ void scatter_fill_kernel(const int* __restrict__ degarr, const int* __restrict__ bh,
                                    int* __restrict__ perm, const int* __restrict__ src,
                                    const int* __restrict__ dst, int* __restrict__ next_pos2,
                                    const float* __restrict__ dinv, int2* __restrict__ edge2) {
    if (blockIdx.x < NB) {
        __shared__ int lh[64];
        __shared__ int lbase[64];
        if (threadIdx.x < 64) {
            lh[threadIdx.x] = 0;
            lbase[threadIdx.x] = bh[threadIdx.x * NB + blockIdx.x];
        }
        __syncthreads();
        int gid = blockIdx.x * 256 + threadIdx.x;
        if (gid < NN) {
            int b = min(degarr[gid], 63);
            int r = atomicAdd(&lh[b], 1);
            perm[lbase[b] + r] = gid;
        }
    } else {
        int bb = blockIdx.x - NB;
        int slice = bb >> 3;
        int r = bb & 7;
        int base = slice * FS;
#pragma unroll 2
        for (int i = threadIdx.x; i < FS; i += 256) {
            int e = base + i;
            if (e < NE) {
                int d = dst[e];
                if (d / CHSZ == r) {
                    int s = src[e];
                    int pos = atomicAdd(&next_pos2[d * NCH + s / CHSZ], 1);
                    int2 o;
                    o.x = s;
                    o.y = __float_as_int(dinv[s] * dinv[d]);
                    edge2[pos] = o;
                }
            }
        }
    }
}

// ---------------- fused per-layer: gather-aggregate + MFMA GEMM + bias+LN+ReLU+residual ----
// R7 shape (known best: ~51us/layer). edge2 read nontemporal (streamed once -> don't evict
// feature slices from L2); epilogue stores nontemporal (no intra-kernel reuse).
template <bool RES, bool FINAL>
__global__ __launch_bounds__(256) void layer_kernel(
    const ushort* __restrict__ fin, const int* __restrict__ row_ptr,
    const int2* __restrict__ edge2, const int* __restrict__ perm,
    const float* __restrict__ dinv, const ushort* __restrict__ Wt,
    const float* __restrict__ bias, const float* __restrict__ gamma,
    const float* __restrict__ beta, ushort* __restrict__ fout, float* __restrict__ out) {
    __shared__ uint4 sA[16 * 17];
    __shared__ int sNode[16];
    __shared__ float sLN1[4][16], sLN2[4][16];

    int w = threadIdx.x >> 6, lane = threadIdx.x & 63;
    int g = lane >> 4, t = lane & 15;
    int arow = w * 4 + g;
    int slot = blockIdx.x * 16 + arow;  // grid 3125*16 = 50000 exact
    int node = perm[slot];
    if (t == 0) sNode[arow] = node;

    // ---- phase 1: gather-aggregate (16 lanes x 16B per node row), x4 pipelined ----
    {
        int beg = row_ptr[node], end = row_ptr[node + 1];
        const uint4* cu4 = (const uint4*)fin;
        const long long* e8 = (const long long*)edge2;
        float acc[8] = {};
        int e = beg;
        for (; e + 4 <= end; e += 4) {
            long long a[4];
            uint4 v[4];
#pragma unroll
            for (int j = 0; j < 4; ++j) a[j] = __builtin_nontemporal_load(&e8[e + j]);
#pragma unroll
            for (int j = 0; j < 4; ++j) v[j] = cu4[((int)a[j]) * 16 + t];
#pragma unroll
            for (int j = 0; j < 4; ++j) {
                uint vv[4] = {v[j].x, v[j].y, v[j].z, v[j].w};
                float ww = __int_as_float((int)(a[j] >> 32));
#pragma unroll
                for (int i = 0; i < 4; ++i) {
                    acc[2 * i] = fmaf(ww, __uint_as_float(vv[i] << 16), acc[2 * i]);
                    acc[2 * i + 1] =
                        fmaf(ww, __uint_as_float(vv[i] & 0xffff0000u), acc[2 * i + 1]);
                }
            }
        }
        for (; e < end; ++e) {
            long long a = __builtin_nontemporal_load(&e8[e]);
            uint4 v = cu4[((int)a) * 16 + t];
            uint vv[4] = {v.x, v.y, v.z, v.w};
            float ww = __int_as_float((int)(a >> 32));
#pragma unroll
            for (int i = 0; i < 4; ++i) {
                acc[2 * i] = fmaf(ww, __uint_as_float(vv[i] << 16), acc[2 * i]);
                acc[2 * i + 1] = fmaf(ww, __uint_as_float(vv[i] & 0xffff0000u), acc[2 * i + 1]);
            }
        }
        float di = dinv[node];
        float w2s = di * di;
        {
            uint4 v = cu4[node * 16 + t];
            uint vv[4] = {v.x, v.y, v.z, v.w};
#pragma unroll
            for (int i = 0; i < 4; ++i) {
                acc[2 * i] = fmaf(w2s, __uint_as_float(vv[i] << 16), acc[2 * i]);
                acc[2 * i + 1] = fmaf(w2s, __uint_as_float(vv[i] & 0xffff0000u), acc[2 * i + 1]);
            }
        }
        union { ushort us[8]; uint4 u; } pk;
#pragma unroll
        for (int i = 0; i < 8; ++i) pk.us[i] = f2bf_bits(acc[i]);
        sA[arow * 17 + t] = pk.u;
    }
    __syncthreads();

    // ---- phase 2: MFMA 16x128 tile; wave w owns col-tiles 2w, 2w+1 ----
    int q = lane >> 4, m = lane & 15;
    f32x4 c0 = (f32x4){0.f, 0.f, 0.f, 0.f};
    f32x4 c1 = (f32x4){0.f, 0.f, 0.f, 0.f};
    int n0 = 16 * (2 * w), n1 = 16 * (2 * w + 1);
#pragma unroll
    for (int kk = 0; kk < 4; ++kk) {
        bf16x8 af = *(const bf16x8*)&sA[m * 17 + kk * 4 + q];
        bf16x8 b0 = *(const bf16x8*)(Wt + (n0 + m) * DD + kk * 32 + q * 8);
        bf16x8 b1 = *(const bf16x8*)(Wt + (n1 + m) * DD + kk * 32 + q * 8);
        c0 = __builtin_amdgcn_mfma_f32_16x16x32_bf16(af, b0, c0, 0, 0, 0);
        c1 = __builtin_amdgcn_mfma_f32_16x16x32_bf16(af, b1, c1, 0, 0, 0);
    }

    // ---- epilogue: bias + LN (in-wave m-reduce, LDS cross-wave combine) + ReLU + res ----
    float bb0 = bias[n0 + m], bb1 = bias[n1 + m];
    float s1[4], s2[4];
#pragma unroll
    for (int r = 0; r < 4; ++r) {
        float v0 = c0[r] + bb0, v1 = c1[r] + bb1;
        c0[r] = v0; c1[r] = v1;
        s1[r] = v0 + v1;
        s2[r] = v0 * v0 + v1 * v1;
    }
#pragma unroll
    for (int off = 1; off <= 8; off <<= 1) {
#pragma unroll
        for (int r = 0; r < 4; ++r) {
            s1[r] += __shfl_xor(s1[r], off, 64);
            s2[r] += __shfl_xor(s2[r], off, 64);
        }
    }
    if (m == 0) {
#pragma unroll
        for (int r = 0; r < 4; ++r) {
            sLN1[w][q * 4 + r] = s1[r];
            sLN2[w][q * 4 + r] = s2[r];
        }
    }
    __syncthreads();
    float ga0 = gamma[n0 + m], ga1 = gamma[n1 + m];
    float be0 = beta[n0 + m], be1 = beta[n1 + m];
#pragma unroll
    for (int r = 0; r < 4; ++r) {
        int row = q * 4 + r;
        float S1 = sLN1[0][row] + sLN1[1][row] + sLN1[2][row] + sLN1[3][row];
        float S2 = sLN2[0][row] + sLN2[1][row] + sLN2[2][row] + sLN2[3][row];
        float mu = S1 * (1.f / 128.f);
        float var = S2 * (1.f / 128.f) - mu * mu;
        float rstd = rsqrtf(var + LN_EPS);
        int nd = sNode[row];
        size_t rb = (size_t)nd * DD;
        float o0 = fmaxf((c0[r] - mu) * rstd * ga0 + be0, 0.f);
        float o1 = fmaxf((c1[r] - mu) * rstd * ga1 + be1, 0.f);
        if (RES) {
            o0 += __uint_as_float(((uint)fin[rb + n0 + m]) << 16);
            o1 += __uint_as_float(((uint)fin[rb + n1 + m]) << 16);
        }
        if (FINAL) {
            __builtin_nontemporal_store(o0, &out[rb + n0 + m]);
            __builtin_nontemporal_store(o1, &out[rb + n1 + m]);
        } else {
            __builtin_nontemporal_store(f2bf_bits(o0), &fout[rb + n0 + m]);
            __builtin_nontemporal_store(f2bf_bits(o1), &fout[rb + n1 + m]);
        }
    }
}

// ---------------- launch ----------------

extern "C" void kernel_launch(void* const* d_in, const int* in_sizes, int n_in,
                              void* d_out, int out_size, void* d_ws, size_t ws_size,
                              hipStream_t stream) {
    const float* x = (const float*)d_in[0];
    const int* edge = (const int*)d_in[1];
    const float* Ws = (const float*)d_in[2];
    const float* bs = (const float*)d_in[3];
    const float* gs = (const float*)d_in[4];
    const float* bes = (const float*)d_in[5];
    float* out = (float*)d_out;
    const int* src = edge;
    const int* dst = edge + NE;

    char* p = (char*)d_ws;
    int* counts2 = (int*)p;     p += (size_t)NC2 * 4;     // scanned in place
    int* bsums = (int*)p;       p += 1024 * 4;
    int* row_ptr = (int*)p;     p += (size_t)(NN + 4) * 4;
    int* next_pos2 = (int*)p;   p += (size_t)NC2 * 4;
    float* dinv = (float*)p;    p += (size_t)NN * 4;
    int* degarr = (int*)p;      p += (size_t)NN * 4;
    int* bh = (int*)p;          p += (size_t)PH * 4;
    int* perm = (int*)p;        p += (size_t)NN * 4;
    int2* edge2 = (int2*)p;     p += (size_t)NE * 8;
    ushort* fb0 = (ushort*)p;   p += (size_t)NN * DD * 2;
    ushort* fb1 = (ushort*)p;   p += (size_t)NN * DD * 2;
    ushort* Wt = (ushort*)p;    p += (size_t)3 * DD * DD * 2;

    hipMemsetAsync(counts2, 0, (size_t)NC2 * 4, stream);
    hist_cast_kernel<<<HB + CB + WB, 256, 0, stream>>>(src, dst, counts2, x, (uint4*)fb0, Ws,
                                                       Wt);
    scan1024_blocks<<<NSB, 1024, 0, stream>>>(counts2, bsums);
    scan_sums1024<<<1, 1024, 0, stream>>>(bsums, NSB);
    finalize_kernel<<<NB, 256, 0, stream>>>(counts2, bsums, row_ptr, next_pos2, dinv, degarr,
                                            bh);
    permscan_kernel<<<1, 1024, 0, stream>>>(bh);
    scatter_fill_kernel<<<NB + NSL * 8, 256, 0, stream>>>(degarr, bh, perm, src, dst,
                                                          next_pos2, dinv, edge2);

    int lg = NN / 16;  // 3125
    layer_kernel<false, false><<<lg, 256, 0, stream>>>(
        fb0, row_ptr, edge2, perm, dinv, Wt, bs, gs, bes, fb1, out);
    layer_kernel<true, false><<<lg, 256, 0, stream>>>(
        fb1, row_ptr, edge2, perm, dinv, Wt + 16384, bs + DD, gs + DD, bes + DD, fb0, out);
    layer_kernel<true, true><<<lg, 256, 0, stream>>>(
        fb0, row_ptr, edge2, perm, dinv, Wt + 32768, bs + 2 * DD, gs + 2 * DD, bes + 2 * DD,
        fb1, out);
}

// Round 11
// 313.209 us; speedup vs baseline: 1.2201x; 1.0588x over previous
//
#include <hip/hip_runtime.h>
#include <hip/hip_bf16.h>

#define NN 50000
#define NE 800000
#define DD 128
#define NB 196             // ceil(NN/256)
#define NCH 8              // source chunks (1.6 MB bf16 slice each)
#define CHSZ 6250          // NN / NCH
#define NC2 (NN * NCH)     // per-(node,chunk) bins = 400000
#define NSB 391            // ceil(NC2/1024)
#define PH (64 * NB)       // degree-bucket histogram size = 12544
#define FS 2048            // fill: edges per slice
#define NSL 391            // ceil(NE/FS)
#define HB 3125            // hist blocks (NE/256)
#define CB 3125            // cast blocks (NN*DD/8/256)
#define WB 192             // wtcast blocks
#define LN_EPS 1e-5f

typedef __bf16 bf16x8 __attribute__((ext_vector_type(8)));
typedef float f32x4 __attribute__((ext_vector_type(4)));

__device__ inline ushort f2bf_bits(float f) {
    union { __hip_bfloat16 h; ushort u; } c;
    c.h = __float2bfloat16(f);
    return c.u;
}

// ---------------- fused: per-(dst,chunk) histogram + feature cast + Wt cast ----------------
__global__ void hist_cast_kernel(const int* __restrict__ src, const int* __restrict__ dst,
                                 int* __restrict__ counts2, const float* __restrict__ x,
                                 uint4* __restrict__ fb0, const float* __restrict__ W,
                                 ushort* __restrict__ Wt) {
    int b = blockIdx.x;
    if (b < HB) {
        int e = b * 256 + threadIdx.x;
        int s = src[e], d = dst[e];
        atomicAdd(&counts2[d * NCH + s / CHSZ], 1);
    } else if (b < HB + CB) {
        int i = (b - HB) * 256 + threadIdx.x;  // 800000 threads x 8 floats
        float4 v0 = ((const float4*)x)[2 * i];
        float4 v1 = ((const float4*)x)[2 * i + 1];
        union { ushort us[8]; uint4 u; } pk;
        pk.us[0] = f2bf_bits(v0.x); pk.us[1] = f2bf_bits(v0.y);
        pk.us[2] = f2bf_bits(v0.z); pk.us[3] = f2bf_bits(v0.w);
        pk.us[4] = f2bf_bits(v1.x); pk.us[5] = f2bf_bits(v1.y);
        pk.us[6] = f2bf_bits(v1.z); pk.us[7] = f2bf_bits(v1.w);
        fb0[i] = pk.u;
    } else {
        int i = (b - HB - CB) * 256 + threadIdx.x;  // 3*128*128 = 49152
        int l = i >> 14, k = (i >> 7) & 127, n = i & 127;
        Wt[l * 16384 + n * 128 + k] = f2bf_bits(W[i]);
    }
}

// level-0 scan over NC2 elements, 1024 threads/block, in-place; emits block sums
__global__ __launch_bounds__(1024) void scan1024_blocks(int* __restrict__ data,
                                                        int* __restrict__ bsums) {
    __shared__ int ws[16];
    int gid = blockIdx.x * 1024 + threadIdx.x;
    int lane = threadIdx.x & 63, wid = threadIdx.x >> 6;
    int v = (gid < NC2) ? data[gid] : 0;
    int x = v;
#pragma unroll
    for (int off = 1; off < 64; off <<= 1) {
        int t = __shfl_up(x, off, 64);
        if (lane >= off) x += t;
    }
    if (lane == 63) ws[wid] = x;
    __syncthreads();
    if (threadIdx.x == 0) {
        int run = 0;
        for (int i = 0; i < 16; ++i) { int t = ws[i]; ws[i] = run; run += t; }
        bsums[blockIdx.x] = run;
    }
    __syncthreads();
    if (gid < NC2) data[gid] = x - v + ws[wid];
}

// level-1: single block scans the 391 block sums
__global__ __launch_bounds__(1024) void scan_sums1024(int* __restrict__ bsums, int nb) {
    __shared__ int ws[16];
    int tid = threadIdx.x;
    int lane = tid & 63, wid = tid >> 6;
    int v = (tid < nb) ? bsums[tid] : 0;
    int x = v;
#pragma unroll
    for (int off = 1; off < 64; off <<= 1) {
        int t = __shfl_up(x, off, 64);
        if (lane >= off) x += t;
    }
    if (lane == 63) ws[wid] = x;
    __syncthreads();
    if (tid == 0) {
        int run = 0;
        for (int i = 0; i < 16; ++i) { int t = ws[i]; ws[i] = run; run += t; }
    }
    __syncthreads();
    if (tid < nb) bsums[tid] = x - v + ws[wid];
}

// absolute cursors, row_ptr, degree, dinv + fused per-block degree histogram
__global__ void finalize_kernel(const int* __restrict__ excl2, const int* __restrict__ bsums,
                                int* __restrict__ row_ptr, int* __restrict__ next_pos2,
                                float* __restrict__ dinv, int* __restrict__ degarr,
                                int* __restrict__ bh) {
    __shared__ int lh[64];
    if (threadIdx.x < 64) lh[threadIdx.x] = 0;
    __syncthreads();
    int d = blockIdx.x * 256 + threadIdx.x;
    if (d < NN) {
        int base = d * NCH;
        int p0 = excl2[base] + bsums[base >> 10];
#pragma unroll
        for (int c = 0; c < NCH; ++c) {
            int idx = base + c;
            next_pos2[idx] = excl2[idx] + bsums[idx >> 10];
        }
        int nxt = (d == NN - 1) ? NE : excl2[base + NCH] + bsums[(base + NCH) >> 10];
        int deg = nxt - p0;
        row_ptr[d] = p0;
        dinv[d] = rsqrtf((float)deg + 1.0f);
        degarr[d] = deg;
        atomicAdd(&lh[min(deg, 63)], 1);
    }
    __syncthreads();
    if (threadIdx.x < 64) bh[threadIdx.x * NB + blockIdx.x] = lh[threadIdx.x];
    if (blockIdx.x == 0 && threadIdx.x == 0) row_ptr[NN] = NE;
}

__global__ __launch_bounds__(1024) void permscan_kernel(int* __restrict__ bh) {
    __shared__ int wsum[16];
    const int CH = 13;  // 1024*13 = 13312 >= 12544
    int tid = threadIdx.x;
    int base = tid * CH;
    int vals[CH];
    int s = 0;
#pragma unroll
    for (int i = 0; i < CH; ++i) {
        int idx = base + i;
        int v = (idx < PH) ? bh[idx] : 0;
        vals[i] = s;
        s += v;
    }
    int lane = tid & 63, wid = tid >> 6;
    int x = s;
#pragma unroll
    for (int off = 1; off < 64; off <<= 1) {
        int t = __shfl_up(x, off, 64);
        if (lane >= off) x += t;
    }
    if (lane == 63) wsum[wid] = x;
    __syncthreads();
    if (tid == 0) {
        int run = 0;
        for (int i = 0; i < 16; ++i) { int t = wsum[i]; wsum[i] = run; run += t; }
    }
    __syncthreads();
    int texcl = x - s + wsum[wid];
#pragma unroll
    for (int i = 0; i < CH; ++i) {
        int idx = base + i;
        if (idx < PH) bh[idx] = texcl + vals[i];
    }
}

// merged: blocks [0,NB) = degree-bucket permscatter; blocks [NB, NB+NSL*8) = XCD-
// partitioned fill (block b scans edge slice ((b-NB)>>3), handles dst range ((b-NB)&7)).
__global__ void scatter_fill_kernel(const int* __restrict__ degarr, const int* __restrict__ bh,
                                    int* __restrict__ perm, const int* __restrict__ src,
                                    const int* __restrict__ dst, int* __restrict__ next_pos2,
                                    const float* __restrict__ dinv, int2* __restrict__ edge2) {
    if (blockIdx.x < NB) {
        __shared__ int lh[64];
        __shared__ int lbase[64];
        if (threadIdx.x < 64) {
            lh[threadIdx.x] = 0;
            lbase[threadIdx.x] = bh[threadIdx.x * NB + blockIdx.x];
        }
        __syncthreads();
        int gid = blockIdx.x * 256 + threadIdx.x;
        if (gid < NN) {
            int b = min(degarr[gid], 63);
            int r = atomicAdd(&lh[b], 1);
            perm[lbase[b] + r] = gid;
        }
    } else {
        int bb = blockIdx.x - NB;
        int slice = bb >> 3;
        int r = bb & 7;
        int base = slice * FS;
#pragma unroll 2
        for (int i = threadIdx.x; i < FS; i += 256) {
            int e = base + i;
            if (e < NE) {
                int d = dst[e];
                if (d / CHSZ == r) {
                    int s = src[e];
                    int pos = atomicAdd(&next_pos2[d * NCH + s / CHSZ], 1);
                    int2 o;
                    o.x = s;
                    o.y = __float_as_int(dinv[s] * dinv[d]);
                    edge2[pos] = o;
                }
            }
        }
    }
}

// ---------------- fused per-layer: gather-aggregate + MFMA GEMM + bias+LN+ReLU+residual ----
// Exact R7 shape (best measured: ~51us/layer). NT hints reverted: R10 showed sub-line NT
// stores force RMW line fetches (+5MB FETCH, +3.7MB WRITE, +7.5us/layer).
template <bool RES, bool FINAL>
__global__ __launch_bounds__(256) void layer_kernel(
    const ushort* __restrict__ fin, const int* __restrict__ row_ptr,
    const int2* __restrict__ edge2, const int* __restrict__ perm,
    const float* __restrict__ dinv, const ushort* __restrict__ Wt,
    const float* __restrict__ bias, const float* __restrict__ gamma,
    const float* __restrict__ beta, ushort* __restrict__ fout, float* __restrict__ out) {
    __shared__ uint4 sA[16 * 17];
    __shared__ int sNode[16];
    __shared__ float sLN1[4][16], sLN2[4][16];

    int w = threadIdx.x >> 6, lane = threadIdx.x & 63;
    int g = lane >> 4, t = lane & 15;
    int arow = w * 4 + g;
    int slot = blockIdx.x * 16 + arow;  // grid 3125*16 = 50000 exact
    int node = perm[slot];
    if (t == 0) sNode[arow] = node;

    // ---- phase 1: gather-aggregate (16 lanes x 16B per node row), x4 pipelined ----
    {
        int beg = row_ptr[node], end = row_ptr[node + 1];
        const uint4* cu4 = (const uint4*)fin;
        float acc[8] = {};
        int e = beg;
        for (; e + 4 <= end; e += 4) {
            int2 a[4];
            uint4 v[4];
#pragma unroll
            for (int j = 0; j < 4; ++j) a[j] = edge2[e + j];
#pragma unroll
            for (int j = 0; j < 4; ++j) v[j] = cu4[a[j].x * 16 + t];
#pragma unroll
            for (int j = 0; j < 4; ++j) {
                uint vv[4] = {v[j].x, v[j].y, v[j].z, v[j].w};
                float ww = __int_as_float(a[j].y);
#pragma unroll
                for (int i = 0; i < 4; ++i) {
                    acc[2 * i] = fmaf(ww, __uint_as_float(vv[i] << 16), acc[2 * i]);
                    acc[2 * i + 1] =
                        fmaf(ww, __uint_as_float(vv[i] & 0xffff0000u), acc[2 * i + 1]);
                }
            }
        }
        for (; e < end; ++e) {
            int2 a = edge2[e];
            uint4 v = cu4[a.x * 16 + t];
            uint vv[4] = {v.x, v.y, v.z, v.w};
            float ww = __int_as_float(a.y);
#pragma unroll
            for (int i = 0; i < 4; ++i) {
                acc[2 * i] = fmaf(ww, __uint_as_float(vv[i] << 16), acc[2 * i]);
                acc[2 * i + 1] = fmaf(ww, __uint_as_float(vv[i] & 0xffff0000u), acc[2 * i + 1]);
            }
        }
        float di = dinv[node];
        float w2s = di * di;
        {
            uint4 v = cu4[node * 16 + t];
            uint vv[4] = {v.x, v.y, v.z, v.w};
#pragma unroll
            for (int i = 0; i < 4; ++i) {
                acc[2 * i] = fmaf(w2s, __uint_as_float(vv[i] << 16), acc[2 * i]);
                acc[2 * i + 1] = fmaf(w2s, __uint_as_float(vv[i] & 0xffff0000u), acc[2 * i + 1]);
            }
        }
        union { ushort us[8]; uint4 u; } pk;
#pragma unroll
        for (int i = 0; i < 8; ++i) pk.us[i] = f2bf_bits(acc[i]);
        sA[arow * 17 + t] = pk.u;
    }
    __syncthreads();

    // ---- phase 2: MFMA 16x128 tile; wave w owns col-tiles 2w, 2w+1 ----
    int q = lane >> 4, m = lane & 15;
    f32x4 c0 = (f32x4){0.f, 0.f, 0.f, 0.f};
    f32x4 c1 = (f32x4){0.f, 0.f, 0.f, 0.f};
    int n0 = 16 * (2 * w), n1 = 16 * (2 * w + 1);
#pragma unroll
    for (int kk = 0; kk < 4; ++kk) {
        bf16x8 af = *(const bf16x8*)&sA[m * 17 + kk * 4 + q];
        bf16x8 b0 = *(const bf16x8*)(Wt + (n0 + m) * DD + kk * 32 + q * 8);
        bf16x8 b1 = *(const bf16x8*)(Wt + (n1 + m) * DD + kk * 32 + q * 8);
        c0 = __builtin_amdgcn_mfma_f32_16x16x32_bf16(af, b0, c0, 0, 0, 0);
        c1 = __builtin_amdgcn_mfma_f32_16x16x32_bf16(af, b1, c1, 0, 0, 0);
    }

    // ---- epilogue: bias + LN (in-wave m-reduce, LDS cross-wave combine) + ReLU + res ----
    float bb0 = bias[n0 + m], bb1 = bias[n1 + m];
    float s1[4], s2[4];
#pragma unroll
    for (int r = 0; r < 4; ++r) {
        float v0 = c0[r] + bb0, v1 = c1[r] + bb1;
        c0[r] = v0; c1[r] = v1;
        s1[r] = v0 + v1;
        s2[r] = v0 * v0 + v1 * v1;
    }
#pragma unroll
    for (int off = 1; off <= 8; off <<= 1) {
#pragma unroll
        for (int r = 0; r < 4; ++r) {
            s1[r] += __shfl_xor(s1[r], off, 64);
            s2[r] += __shfl_xor(s2[r], off, 64);
        }
    }
    if (m == 0) {
#pragma unroll
        for (int r = 0; r < 4; ++r) {
            sLN1[w][q * 4 + r] = s1[r];
            sLN2[w][q * 4 + r] = s2[r];
        }
    }
    __syncthreads();
    float ga0 = gamma[n0 + m], ga1 = gamma[n1 + m];
    float be0 = beta[n0 + m], be1 = beta[n1 + m];
#pragma unroll
    for (int r = 0; r < 4; ++r) {
        int row = q * 4 + r;
        float S1 = sLN1[0][row] + sLN1[1][row] + sLN1[2][row] + sLN1[3][row];
        float S2 = sLN2[0][row] + sLN2[1][row] + sLN2[2][row] + sLN2[3][row];
        float mu = S1 * (1.f / 128.f);
        float var = S2 * (1.f / 128.f) - mu * mu;
        float rstd = rsqrtf(var + LN_EPS);
        int nd = sNode[row];
        size_t rb = (size_t)nd * DD;
        float o0 = fmaxf((c0[r] - mu) * rstd * ga0 + be0, 0.f);
        float o1 = fmaxf((c1[r] - mu) * rstd * ga1 + be1, 0.f);
        if (RES) {
            o0 += __uint_as_float(((uint)fin[rb + n0 + m]) << 16);
            o1 += __uint_as_float(((uint)fin[rb + n1 + m]) << 16);
        }
        if (FINAL) {
            out[rb + n0 + m] = o0;
            out[rb + n1 + m] = o1;
        } else {
            fout[rb + n0 + m] = f2bf_bits(o0);
            fout[rb + n1 + m] = f2bf_bits(o1);
        }
    }
}

// ---------------- launch ----------------

extern "C" void kernel_launch(void* const* d_in, const int* in_sizes, int n_in,
                              void* d_out, int out_size, void* d_ws, size_t ws_size,
                              hipStream_t stream) {
    const float* x = (const float*)d_in[0];
    const int* edge = (const int*)d_in[1];
    const float* Ws = (const float*)d_in[2];
    const float* bs = (const float*)d_in[3];
    const float* gs = (const float*)d_in[4];
    const float* bes = (const float*)d_in[5];
    float* out = (float*)d_out;
    const int* src = edge;
    const int* dst = edge + NE;

    char* p = (char*)d_ws;
    int* counts2 = (int*)p;     p += (size_t)NC2 * 4;     // scanned in place
    int* bsums = (int*)p;       p += 1024 * 4;
    int* row_ptr = (int*)p;     p += (size_t)(NN + 4) * 4;
    int* next_pos2 = (int*)p;   p += (size_t)NC2 * 4;
    float* dinv = (float*)p;    p += (size_t)NN * 4;
    int* degarr = (int*)p;      p += (size_t)NN * 4;
    int* bh = (int*)p;          p += (size_t)PH * 4;
    int* perm = (int*)p;        p += (size_t)NN * 4;
    int2* edge2 = (int2*)p;     p += (size_t)NE * 8;
    ushort* fb0 = (ushort*)p;   p += (size_t)NN * DD * 2;
    ushort* fb1 = (ushort*)p;   p += (size_t)NN * DD * 2;
    ushort* Wt = (ushort*)p;    p += (size_t)3 * DD * DD * 2;

    hipMemsetAsync(counts2, 0, (size_t)NC2 * 4, stream);
    hist_cast_kernel<<<HB + CB + WB, 256, 0, stream>>>(src, dst, counts2, x, (uint4*)fb0, Ws,
                                                       Wt);
    scan1024_blocks<<<NSB, 1024, 0, stream>>>(counts2, bsums);
    scan_sums1024<<<1, 1024, 0, stream>>>(bsums, NSB);
    finalize_kernel<<<NB, 256, 0, stream>>>(counts2, bsums, row_ptr, next_pos2, dinv, degarr,
                                            bh);
    permscan_kernel<<<1, 1024, 0, stream>>>(bh);
    scatter_fill_kernel<<<NB + NSL * 8, 256, 0, stream>>>(degarr, bh, perm, src, dst,
                                                          next_pos2, dinv, edge2);

    int lg = NN / 16;  // 3125
    layer_kernel<false, false><<<lg, 256, 0, stream>>>(
        fb0, row_ptr, edge2, perm, dinv, Wt, bs, gs, bes, fb1, out);
    layer_kernel<true, false><<<lg, 256, 0, stream>>>(
        fb1, row_ptr, edge2, perm, dinv, Wt + 16384, bs + DD, gs + DD, bes + DD, fb0, out);
    layer_kernel<true, true><<<lg, 256, 0, stream>>>(
        fb0, row_ptr, edge2, perm, dinv, Wt + 32768, bs + 2 * DD, gs + 2 * DD, bes + 2 * DD,
        fb1, out);
}

// Round 12
// 312.120 us; speedup vs baseline: 1.2243x; 1.0035x over previous
//
#include <hip/hip_runtime.h>
#include <hip/hip_bf16.h>

#define NN 50000
#define NE 800000
#define DD 128
#define NB 196             // ceil(NN/256)
#define NCH 8              // source chunks (1.6 MB bf16 slice each)
#define CHSZ 6250          // NN / NCH
#define NC2 (NN * NCH)     // per-(node,chunk) bins = 400000
#define NSB 391            // ceil(NC2/1024)
#define PH (64 * NB)       // degree-bucket histogram size = 12544
#define FS 2048            // edges per slice (hist + fill partitioning)
#define NSL 391            // ceil(NE/FS)
#define HHB (NSL * 8)      // hist blocks, XCD-partitioned = 3128
#define CB 3125            // cast blocks (NN*DD/8/256)
#define WB 192             // wtcast blocks
#define LN_EPS 1e-5f

typedef __bf16 bf16x8 __attribute__((ext_vector_type(8)));
typedef float f32x4 __attribute__((ext_vector_type(4)));

__device__ inline ushort f2bf_bits(float f) {
    union { __hip_bfloat16 h; ushort u; } c;
    c.h = __float2bfloat16(f);
    return c.u;
}

// ---- fused: XCD-partitioned per-(dst,chunk) histogram + feature cast + Wt cast ----
// Hist partitioned like fill: block b scans edge slice (b>>3), handles dst range (b&7).
// Each XCD's atomics then land in its own 200KB counts2 window (L2-local lines) instead
// of bouncing 800k random atomics across 8 L2s.
__global__ void hist_cast_kernel(const int* __restrict__ src, const int* __restrict__ dst,
                                 int* __restrict__ counts2, const float* __restrict__ x,
                                 uint4* __restrict__ fb0, const float* __restrict__ W,
                                 ushort* __restrict__ Wt) {
    int b = blockIdx.x;
    if (b < HHB) {
        int slice = b >> 3;
        int r = b & 7;
        int base = slice * FS;
#pragma unroll 2
        for (int i = threadIdx.x; i < FS; i += 256) {
            int e = base + i;
            if (e < NE) {
                int d = dst[e];
                if (d / CHSZ == r) {
                    int s = src[e];
                    atomicAdd(&counts2[d * NCH + s / CHSZ], 1);
                }
            }
        }
    } else if (b < HHB + CB) {
        int i = (b - HHB) * 256 + threadIdx.x;  // 800000 threads x 8 floats
        float4 v0 = ((const float4*)x)[2 * i];
        float4 v1 = ((const float4*)x)[2 * i + 1];
        union { ushort us[8]; uint4 u; } pk;
        pk.us[0] = f2bf_bits(v0.x); pk.us[1] = f2bf_bits(v0.y);
        pk.us[2] = f2bf_bits(v0.z); pk.us[3] = f2bf_bits(v0.w);
        pk.us[4] = f2bf_bits(v1.x); pk.us[5] = f2bf_bits(v1.y);
        pk.us[6] = f2bf_bits(v1.z); pk.us[7] = f2bf_bits(v1.w);
        fb0[i] = pk.u;
    } else {
        int i = (b - HHB - CB) * 256 + threadIdx.x;  // 3*128*128 = 49152
        int l = i >> 14, k = (i >> 7) & 127, n = i & 127;
        Wt[l * 16384 + n * 128 + k] = f2bf_bits(W[i]);
    }
}

// level-0 scan over NC2 elements, 1024 threads/block, in-place; emits block sums
__global__ __launch_bounds__(1024) void scan1024_blocks(int* __restrict__ data,
                                                        int* __restrict__ bsums) {
    __shared__ int ws[16];
    int gid = blockIdx.x * 1024 + threadIdx.x;
    int lane = threadIdx.x & 63, wid = threadIdx.x >> 6;
    int v = (gid < NC2) ? data[gid] : 0;
    int x = v;
#pragma unroll
    for (int off = 1; off < 64; off <<= 1) {
        int t = __shfl_up(x, off, 64);
        if (lane >= off) x += t;
    }
    if (lane == 63) ws[wid] = x;
    __syncthreads();
    if (threadIdx.x == 0) {
        int run = 0;
        for (int i = 0; i < 16; ++i) { int t = ws[i]; ws[i] = run; run += t; }
        bsums[blockIdx.x] = run;
    }
    __syncthreads();
    if (gid < NC2) data[gid] = x - v + ws[wid];
}

// level-1: single block scans the 391 block sums
__global__ __launch_bounds__(1024) void scan_sums1024(int* __restrict__ bsums, int nb) {
    __shared__ int ws[16];
    int tid = threadIdx.x;
    int lane = tid & 63, wid = tid >> 6;
    int v = (tid < nb) ? bsums[tid] : 0;
    int x = v;
#pragma unroll
    for (int off = 1; off < 64; off <<= 1) {
        int t = __shfl_up(x, off, 64);
        if (lane >= off) x += t;
    }
    if (lane == 63) ws[wid] = x;
    __syncthreads();
    if (tid == 0) {
        int run = 0;
        for (int i = 0; i < 16; ++i) { int t = ws[i]; ws[i] = run; run += t; }
    }
    __syncthreads();
    if (tid < nb) bsums[tid] = x - v + ws[wid];
}

// absolute cursors, row_ptr, degree, dinv + fused per-block degree histogram
__global__ void finalize_kernel(const int* __restrict__ excl2, const int* __restrict__ bsums,
                                int* __restrict__ row_ptr, int* __restrict__ next_pos2,
                                float* __restrict__ dinv, int* __restrict__ degarr,
                                int* __restrict__ bh) {
    __shared__ int lh[64];
    if (threadIdx.x < 64) lh[threadIdx.x] = 0;
    __syncthreads();
    int d = blockIdx.x * 256 + threadIdx.x;
    if (d < NN) {
        int base = d * NCH;
        int p0 = excl2[base] + bsums[base >> 10];
#pragma unroll
        for (int c = 0; c < NCH; ++c) {
            int idx = base + c;
            next_pos2[idx] = excl2[idx] + bsums[idx >> 10];
        }
        int nxt = (d == NN - 1) ? NE : excl2[base + NCH] + bsums[(base + NCH) >> 10];
        int deg = nxt - p0;
        row_ptr[d] = p0;
        dinv[d] = rsqrtf((float)deg + 1.0f);
        degarr[d] = deg;
        atomicAdd(&lh[min(deg, 63)], 1);
    }
    __syncthreads();
    if (threadIdx.x < 64) bh[threadIdx.x * NB + blockIdx.x] = lh[threadIdx.x];
    if (blockIdx.x == 0 && threadIdx.x == 0) row_ptr[NN] = NE;
}

__global__ __launch_bounds__(1024) void permscan_kernel(int* __restrict__ bh) {
    __shared__ int wsum[16];
    const int CH = 13;  // 1024*13 = 13312 >= 12544
    int tid = threadIdx.x;
    int base = tid * CH;
    int vals[CH];
    int s = 0;
#pragma unroll
    for (int i = 0; i < CH; ++i) {
        int idx = base + i;
        int v = (idx < PH) ? bh[idx] : 0;
        vals[i] = s;
        s += v;
    }
    int lane = tid & 63, wid = tid >> 6;
    int x = s;
#pragma unroll
    for (int off = 1; off < 64; off <<= 1) {
        int t = __shfl_up(x, off, 64);
        if (lane >= off) x += t;
    }
    if (lane == 63) wsum[wid] = x;
    __syncthreads();
    if (tid == 0) {
        int run = 0;
        for (int i = 0; i < 16; ++i) { int t = wsum[i]; wsum[i] = run; run += t; }
    }
    __syncthreads();
    int texcl = x - s + wsum[wid];
#pragma unroll
    for (int i = 0; i < CH; ++i) {
        int idx = base + i;
        if (idx < PH) bh[idx] = texcl + vals[i];
    }
}

// merged: blocks [0,NB) = degree-bucket permscatter; blocks [NB, NB+NSL*8) = XCD-
// partitioned fill (block b scans edge slice ((b-NB)>>3), handles dst range ((b-NB)&7)).
__global__ void scatter_fill_kernel(const int* __restrict__ degarr, const int* __restrict__ bh,
                                    int* __restrict__ perm, const int* __restrict__ src,
                                    const int* __restrict__ dst, int* __restrict__ next_pos2,
                                    const float* __restrict__ dinv, int2* __restrict__ edge2) {
    if (blockIdx.x < NB) {
        __shared__ int lh[64];
        __shared__ int lbase[64];
        if (threadIdx.x < 64) {
            lh[threadIdx.x] = 0;
            lbase[threadIdx.x] = bh[threadIdx.x * NB + blockIdx.x];
        }
        __syncthreads();
        int gid = blockIdx.x * 256 + threadIdx.x;
        if (gid < NN) {
            int b = min(degarr[gid], 63);
            int r = atomicAdd(&lh[b], 1);
            perm[lbase[b] + r] = gid;
        }
    } else {
        int bb = blockIdx.x - NB;
        int slice = bb >> 3;
        int r = bb & 7;
        int base = slice * FS;
#pragma unroll 2
        for (int i = threadIdx.x; i < FS; i += 256) {
            int e = base + i;
            if (e < NE) {
                int d = dst[e];
                if (d / CHSZ == r) {
                    int s = src[e];
                    int pos = atomicAdd(&next_pos2[d * NCH + s / CHSZ], 1);
                    int2 o;
                    o.x = s;
                    o.y = __float_as_int(dinv[s] * dinv[d]);
                    edge2[pos] = o;
                }
            }
        }
    }
}

// ---------------- fused per-layer: gather-aggregate + MFMA GEMM + bias+LN+ReLU+residual ----
// Exact R7 shape (best measured: ~50.6us/layer, ~15% above the 44us random-line floor).
template <bool RES, bool FINAL>
__global__ __launch_bounds__(256) void layer_kernel(
    const ushort* __restrict__ fin, const int* __restrict__ row_ptr,
    const int2* __restrict__ edge2, const int* __restrict__ perm,
    const float* __restrict__ dinv, const ushort* __restrict__ Wt,
    const float* __restrict__ bias, const float* __restrict__ gamma,
    const float* __restrict__ beta, ushort* __restrict__ fout, float* __restrict__ out) {
    __shared__ uint4 sA[16 * 17];
    __shared__ int sNode[16];
    __shared__ float sLN1[4][16], sLN2[4][16];

    int w = threadIdx.x >> 6, lane = threadIdx.x & 63;
    int g = lane >> 4, t = lane & 15;
    int arow = w * 4 + g;
    int slot = blockIdx.x * 16 + arow;  // grid 3125*16 = 50000 exact
    int node = perm[slot];
    if (t == 0) sNode[arow] = node;

    // ---- phase 1: gather-aggregate (16 lanes x 16B per node row), x4 pipelined ----
    {
        int beg = row_ptr[node], end = row_ptr[node + 1];
        const uint4* cu4 = (const uint4*)fin;
        float acc[8] = {};
        int e = beg;
        for (; e + 4 <= end; e += 4) {
            int2 a[4];
            uint4 v[4];
#pragma unroll
            for (int j = 0; j < 4; ++j) a[j] = edge2[e + j];
#pragma unroll
            for (int j = 0; j < 4; ++j) v[j] = cu4[a[j].x * 16 + t];
#pragma unroll
            for (int j = 0; j < 4; ++j) {
                uint vv[4] = {v[j].x, v[j].y, v[j].z, v[j].w};
                float ww = __int_as_float(a[j].y);
#pragma unroll
                for (int i = 0; i < 4; ++i) {
                    acc[2 * i] = fmaf(ww, __uint_as_float(vv[i] << 16), acc[2 * i]);
                    acc[2 * i + 1] =
                        fmaf(ww, __uint_as_float(vv[i] & 0xffff0000u), acc[2 * i + 1]);
                }
            }
        }
        for (; e < end; ++e) {
            int2 a = edge2[e];
            uint4 v = cu4[a.x * 16 + t];
            uint vv[4] = {v.x, v.y, v.z, v.w};
            float ww = __int_as_float(a.y);
#pragma unroll
            for (int i = 0; i < 4; ++i) {
                acc[2 * i] = fmaf(ww, __uint_as_float(vv[i] << 16), acc[2 * i]);
                acc[2 * i + 1] = fmaf(ww, __uint_as_float(vv[i] & 0xffff0000u), acc[2 * i + 1]);
            }
        }
        float di = dinv[node];
        float w2s = di * di;
        {
            uint4 v = cu4[node * 16 + t];
            uint vv[4] = {v.x, v.y, v.z, v.w};
#pragma unroll
            for (int i = 0; i < 4; ++i) {
                acc[2 * i] = fmaf(w2s, __uint_as_float(vv[i] << 16), acc[2 * i]);
                acc[2 * i + 1] = fmaf(w2s, __uint_as_float(vv[i] & 0xffff0000u), acc[2 * i + 1]);
            }
        }
        union { ushort us[8]; uint4 u; } pk;
#pragma unroll
        for (int i = 0; i < 8; ++i) pk.us[i] = f2bf_bits(acc[i]);
        sA[arow * 17 + t] = pk.u;
    }
    __syncthreads();

    // ---- phase 2: MFMA 16x128 tile; wave w owns col-tiles 2w, 2w+1 ----
    int q = lane >> 4, m = lane & 15;
    f32x4 c0 = (f32x4){0.f, 0.f, 0.f, 0.f};
    f32x4 c1 = (f32x4){0.f, 0.f, 0.f, 0.f};
    int n0 = 16 * (2 * w), n1 = 16 * (2 * w + 1);
#pragma unroll
    for (int kk = 0; kk < 4; ++kk) {
        bf16x8 af = *(const bf16x8*)&sA[m * 17 + kk * 4 + q];
        bf16x8 b0 = *(const bf16x8*)(Wt + (n0 + m) * DD + kk * 32 + q * 8);
        bf16x8 b1 = *(const bf16x8*)(Wt + (n1 + m) * DD + kk * 32 + q * 8);
        c0 = __builtin_amdgcn_mfma_f32_16x16x32_bf16(af, b0, c0, 0, 0, 0);
        c1 = __builtin_amdgcn_mfma_f32_16x16x32_bf16(af, b1, c1, 0, 0, 0);
    }

    // ---- epilogue: bias + LN (in-wave m-reduce, LDS cross-wave combine) + ReLU + res ----
    float bb0 = bias[n0 + m], bb1 = bias[n1 + m];
    float s1[4], s2[4];
#pragma unroll
    for (int r = 0; r < 4; ++r) {
        float v0 = c0[r] + bb0, v1 = c1[r] + bb1;
        c0[r] = v0; c1[r] = v1;
        s1[r] = v0 + v1;
        s2[r] = v0 * v0 + v1 * v1;
    }
#pragma unroll
    for (int off = 1; off <= 8; off <<= 1) {
#pragma unroll
        for (int r = 0; r < 4; ++r) {
            s1[r] += __shfl_xor(s1[r], off, 64);
            s2[r] += __shfl_xor(s2[r], off, 64);
        }
    }
    if (m == 0) {
#pragma unroll
        for (int r = 0; r < 4; ++r) {
            sLN1[w][q * 4 + r] = s1[r];
            sLN2[w][q * 4 + r] = s2[r];
        }
    }
    __syncthreads();
    float ga0 = gamma[n0 + m], ga1 = gamma[n1 + m];
    float be0 = beta[n0 + m], be1 = beta[n1 + m];
#pragma unroll
    for (int r = 0; r < 4; ++r) {
        int row = q * 4 + r;
        float S1 = sLN1[0][row] + sLN1[1][row] + sLN1[2][row] + sLN1[3][row];
        float S2 = sLN2[0][row] + sLN2[1][row] + sLN2[2][row] + sLN2[3][row];
        float mu = S1 * (1.f / 128.f);
        float var = S2 * (1.f / 128.f) - mu * mu;
        float rstd = rsqrtf(var + LN_EPS);
        int nd = sNode[row];
        size_t rb = (size_t)nd * DD;
        float o0 = fmaxf((c0[r] - mu) * rstd * ga0 + be0, 0.f);
        float o1 = fmaxf((c1[r] - mu) * rstd * ga1 + be1, 0.f);
        if (RES) {
            o0 += __uint_as_float(((uint)fin[rb + n0 + m]) << 16);
            o1 += __uint_as_float(((uint)fin[rb + n1 + m]) << 16);
        }
        if (FINAL) {
            out[rb + n0 + m] = o0;
            out[rb + n1 + m] = o1;
        } else {
            fout[rb + n0 + m] = f2bf_bits(o0);
            fout[rb + n1 + m] = f2bf_bits(o1);
        }
    }
}

// ---------------- launch ----------------

extern "C" void kernel_launch(void* const* d_in, const int* in_sizes, int n_in,
                              void* d_out, int out_size, void* d_ws, size_t ws_size,
                              hipStream_t stream) {
    const float* x = (const float*)d_in[0];
    const int* edge = (const int*)d_in[1];
    const float* Ws = (const float*)d_in[2];
    const float* bs = (const float*)d_in[3];
    const float* gs = (const float*)d_in[4];
    const float* bes = (const float*)d_in[5];
    float* out = (float*)d_out;
    const int* src = edge;
    const int* dst = edge + NE;

    char* p = (char*)d_ws;
    int* counts2 = (int*)p;     p += (size_t)NC2 * 4;     // scanned in place
    int* bsums = (int*)p;       p += 1024 * 4;
    int* row_ptr = (int*)p;     p += (size_t)(NN + 4) * 4;
    int* next_pos2 = (int*)p;   p += (size_t)NC2 * 4;
    float* dinv = (float*)p;    p += (size_t)NN * 4;
    int* degarr = (int*)p;      p += (size_t)NN * 4;
    int* bh = (int*)p;          p += (size_t)PH * 4;
    int* perm = (int*)p;        p += (size_t)NN * 4;
    int2* edge2 = (int2*)p;     p += (size_t)NE * 8;
    ushort* fb0 = (ushort*)p;   p += (size_t)NN * DD * 2;
    ushort* fb1 = (ushort*)p;   p += (size_t)NN * DD * 2;
    ushort* Wt = (ushort*)p;    p += (size_t)3 * DD * DD * 2;

    hipMemsetAsync(counts2, 0, (size_t)NC2 * 4, stream);
    hist_cast_kernel<<<HHB + CB + WB, 256, 0, stream>>>(src, dst, counts2, x, (uint4*)fb0, Ws,
                                                        Wt);
    scan1024_blocks<<<NSB, 1024, 0, stream>>>(counts2, bsums);
    scan_sums1024<<<1, 1024, 0, stream>>>(bsums, NSB);
    finalize_kernel<<<NB, 256, 0, stream>>>(counts2, bsums, row_ptr, next_pos2, dinv, degarr,
                                            bh);
    permscan_kernel<<<1, 1024, 0, stream>>>(bh);
    scatter_fill_kernel<<<NB + NSL * 8, 256, 0, stream>>>(degarr, bh, perm, src, dst,
                                                          next_pos2, dinv, edge2);

    int lg = NN / 16;  // 3125
    layer_kernel<false, false><<<lg, 256, 0, stream>>>(
        fb0, row_ptr, edge2, perm, dinv, Wt, bs, gs, bes, fb1, out);
    layer_kernel<true, false><<<lg, 256, 0, stream>>>(
        fb1, row_ptr, edge2, perm, dinv, Wt + 16384, bs + DD, gs + DD, bes + DD, fb0, out);
    layer_kernel<true, true><<<lg, 256, 0, stream>>>(
        fb0, row_ptr, edge2, perm, dinv, Wt + 32768, bs + 2 * DD, gs + 2 * DD, bes + 2 * DD,
        fb1, out);
}

// Round 13
// 301.164 us; speedup vs baseline: 1.2688x; 1.0364x over previous
//
#include <hip/hip_runtime.h>
#include <hip/hip_bf16.h>

#define NN 50000
#define NE 800000
#define DD 128
#define NB 196             // ceil(NN/256)
#define NCH 8              // source chunks
#define CHSZ 6250          // NN / NCH
#define NC2 (NN * NCH)     // per-(node,chunk) bins = 400000
#define NSB 391            // ceil(NC2/1024)
#define PH (64 * NB)       // degree-bucket histogram size = 12544
#define FS 2048            // edges per slice (hist + fill partitioning)
#define NSL 391            // ceil(NE/FS)
#define HHB (NSL * 8)      // hist blocks, XCD-partitioned = 3128
#define QB 3125            // quant-cast blocks (NN/16)
#define WB 192             // wtcast blocks
#define LN_EPS 1e-5f

typedef __bf16 bf16x8 __attribute__((ext_vector_type(8)));
typedef float f32x4 __attribute__((ext_vector_type(4)));

__device__ inline ushort f2bf_bits(float f) {
    union { __hip_bfloat16 h; ushort u; } c;
    c.h = __float2bfloat16(f);
    return c.u;
}

// ---- fused: XCD-partitioned per-(dst,chunk) histogram + int8 row-quant cast + Wt cast ----
__global__ void hist_cast_kernel(const int* __restrict__ src, const int* __restrict__ dst,
                                 int* __restrict__ counts2, const float* __restrict__ x,
                                 uint2* __restrict__ qf0, float* __restrict__ sc0,
                                 const float* __restrict__ W, ushort* __restrict__ Wt) {
    int b = blockIdx.x;
    if (b < HHB) {
        int slice = b >> 3;
        int r = b & 7;
        int base = slice * FS;
#pragma unroll 2
        for (int i = threadIdx.x; i < FS; i += 256) {
            int e = base + i;
            if (e < NE) {
                int d = dst[e];
                if (d / CHSZ == r) {
                    int s = src[e];
                    atomicAdd(&counts2[d * NCH + s / CHSZ], 1);
                }
            }
        }
    } else if (b < HHB + QB) {
        // per-node int8 quantization: 16 lanes x 8 floats = one 128-elem row
        int bb = b - HHB;
        int group = threadIdx.x >> 4, t = threadIdx.x & 15;
        int node = bb * 16 + group;  // 3125*16 = 50000 exact
        const float4* xr = (const float4*)(x + (size_t)node * DD + t * 8);
        float4 v0 = xr[0], v1 = xr[1];
        float vals[8] = {v0.x, v0.y, v0.z, v0.w, v1.x, v1.y, v1.z, v1.w};
        float am = 0.f;
#pragma unroll
        for (int i = 0; i < 8; ++i) am = fmaxf(am, fabsf(vals[i]));
#pragma unroll
        for (int off = 1; off <= 8; off <<= 1) am = fmaxf(am, __shfl_xor(am, off, 64));
        float inv = 127.f / fmaxf(am, 1e-20f);
        uint lo = 0, hi = 0;
#pragma unroll
        for (int i = 0; i < 4; ++i) {
            int q = __float2int_rn(vals[i] * inv);
            lo |= ((uint)(q & 0xff)) << (8 * i);
        }
#pragma unroll
        for (int i = 0; i < 4; ++i) {
            int q = __float2int_rn(vals[4 + i] * inv);
            hi |= ((uint)(q & 0xff)) << (8 * i);
        }
        uint2 pk; pk.x = lo; pk.y = hi;
        qf0[node * 16 + t] = pk;
        if (t == 0) sc0[node] = am / 127.f;
    } else {
        int i = (b - HHB - QB) * 256 + threadIdx.x;  // 3*128*128 = 49152
        int l = i >> 14, k = (i >> 7) & 127, n = i & 127;
        Wt[l * 16384 + n * 128 + k] = f2bf_bits(W[i]);
    }
}

// level-0 scan over NC2 elements, 1024 threads/block, in-place; emits block sums
__global__ __launch_bounds__(1024) void scan1024_blocks(int* __restrict__ data,
                                                        int* __restrict__ bsums) {
    __shared__ int ws[16];
    int gid = blockIdx.x * 1024 + threadIdx.x;
    int lane = threadIdx.x & 63, wid = threadIdx.x >> 6;
    int v = (gid < NC2) ? data[gid] : 0;
    int x = v;
#pragma unroll
    for (int off = 1; off < 64; off <<= 1) {
        int t = __shfl_up(x, off, 64);
        if (lane >= off) x += t;
    }
    if (lane == 63) ws[wid] = x;
    __syncthreads();
    if (threadIdx.x == 0) {
        int run = 0;
        for (int i = 0; i < 16; ++i) { int t = ws[i]; ws[i] = run; run += t; }
        bsums[blockIdx.x] = run;
    }
    __syncthreads();
    if (gid < NC2) data[gid] = x - v + ws[wid];
}

// level-1: single block scans the 391 block sums
__global__ __launch_bounds__(1024) void scan_sums1024(int* __restrict__ bsums, int nb) {
    __shared__ int ws[16];
    int tid = threadIdx.x;
    int lane = tid & 63, wid = tid >> 6;
    int v = (tid < nb) ? bsums[tid] : 0;
    int x = v;
#pragma unroll
    for (int off = 1; off < 64; off <<= 1) {
        int t = __shfl_up(x, off, 64);
        if (lane >= off) x += t;
    }
    if (lane == 63) ws[wid] = x;
    __syncthreads();
    if (tid == 0) {
        int run = 0;
        for (int i = 0; i < 16; ++i) { int t = ws[i]; ws[i] = run; run += t; }
    }
    __syncthreads();
    if (tid < nb) bsums[tid] = x - v + ws[wid];
}

// absolute cursors, row_ptr, degree, dinv + fused per-block degree histogram
__global__ void finalize_kernel(const int* __restrict__ excl2, const int* __restrict__ bsums,
                                int* __restrict__ row_ptr, int* __restrict__ next_pos2,
                                float* __restrict__ dinv, int* __restrict__ degarr,
                                int* __restrict__ bh) {
    __shared__ int lh[64];
    if (threadIdx.x < 64) lh[threadIdx.x] = 0;
    __syncthreads();
    int d = blockIdx.x * 256 + threadIdx.x;
    if (d < NN) {
        int base = d * NCH;
        int p0 = excl2[base] + bsums[base >> 10];
#pragma unroll
        for (int c = 0; c < NCH; ++c) {
            int idx = base + c;
            next_pos2[idx] = excl2[idx] + bsums[idx >> 10];
        }
        int nxt = (d == NN - 1) ? NE : excl2[base + NCH] + bsums[(base + NCH) >> 10];
        int deg = nxt - p0;
        row_ptr[d] = p0;
        dinv[d] = rsqrtf((float)deg + 1.0f);
        degarr[d] = deg;
        atomicAdd(&lh[min(deg, 63)], 1);
    }
    __syncthreads();
    if (threadIdx.x < 64) bh[threadIdx.x * NB + blockIdx.x] = lh[threadIdx.x];
    if (blockIdx.x == 0 && threadIdx.x == 0) row_ptr[NN] = NE;
}

__global__ __launch_bounds__(1024) void permscan_kernel(int* __restrict__ bh) {
    __shared__ int wsum[16];
    const int CH = 13;  // 1024*13 = 13312 >= 12544
    int tid = threadIdx.x;
    int base = tid * CH;
    int vals[CH];
    int s = 0;
#pragma unroll
    for (int i = 0; i < CH; ++i) {
        int idx = base + i;
        int v = (idx < PH) ? bh[idx] : 0;
        vals[i] = s;
        s += v;
    }
    int lane = tid & 63, wid = tid >> 6;
    int x = s;
#pragma unroll
    for (int off = 1; off < 64; off <<= 1) {
        int t = __shfl_up(x, off, 64);
        if (lane >= off) x += t;
    }
    if (lane == 63) wsum[wid] = x;
    __syncthreads();
    if (tid == 0) {
        int run = 0;
        for (int i = 0; i < 16; ++i) { int t = wsum[i]; wsum[i] = run; run += t; }
    }
    __syncthreads();
    int texcl = x - s + wsum[wid];
#pragma unroll
    for (int i = 0; i < CH; ++i) {
        int idx = base + i;
        if (idx < PH) bh[idx] = texcl + vals[i];
    }
}

// merged: blocks [0,NB) = degree-bucket permscatter; blocks [NB, NB+NSL*8) = XCD-
// partitioned fill.
__global__ void scatter_fill_kernel(const int* __restrict__ degarr, const int* __restrict__ bh,
                                    int* __restrict__ perm, const int* __restrict__ src,
                                    const int* __restrict__ dst, int* __restrict__ next_pos2,
                                    const float* __restrict__ dinv, int2* __restrict__ edge2) {
    if (blockIdx.x < NB) {
        __shared__ int lh[64];
        __shared__ int lbase[64];
        if (threadIdx.x < 64) {
            lh[threadIdx.x] = 0;
            lbase[threadIdx.x] = bh[threadIdx.x * NB + blockIdx.x];
        }
        __syncthreads();
        int gid = blockIdx.x * 256 + threadIdx.x;
        if (gid < NN) {
            int b = min(degarr[gid], 63);
            int r = atomicAdd(&lh[b], 1);
            perm[lbase[b] + r] = gid;
        }
    } else {
        int bb = blockIdx.x - NB;
        int slice = bb >> 3;
        int r = bb & 7;
        int base = slice * FS;
#pragma unroll 2
        for (int i = threadIdx.x; i < FS; i += 256) {
            int e = base + i;
            if (e < NE) {
                int d = dst[e];
                if (d / CHSZ == r) {
                    int s = src[e];
                    int pos = atomicAdd(&next_pos2[d * NCH + s / CHSZ], 1);
                    int2 o;
                    o.x = s;
                    o.y = __float_as_int(dinv[s] * dinv[d]);
                    edge2[pos] = o;
                }
            }
        }
    }
}

// ---------------- fused per-layer: int8 gather-aggregate + MFMA GEMM + bias+LN+ReLU+res ----
// Gather table is int8 row-quantized (128B row = 2 cache lines vs 4 for bf16) -> halves the
// random line refill that bounds the kernel (R8-R12 evidence: ~2.7 TB/s refill ceiling).
// Aggregation fp32, MFMA bf16, residual chain bf16, final out fp32.
template <bool RES, bool FINAL>
__global__ __launch_bounds__(256) void layer_kernel(
    const uint2* __restrict__ qin, const float* __restrict__ scin,
    const ushort* __restrict__ fin, const int* __restrict__ row_ptr,
    const int2* __restrict__ edge2, const int* __restrict__ perm,
    const float* __restrict__ dinv, const ushort* __restrict__ Wt,
    const float* __restrict__ bias, const float* __restrict__ gamma,
    const float* __restrict__ beta, ushort* __restrict__ fout, char* __restrict__ qfout,
    float* __restrict__ scout, float* __restrict__ out) {
    __shared__ uint4 sA[16 * 17];
    __shared__ int sNode[16];
    __shared__ float sLN1[4][16], sLN2[4][16];
    __shared__ float sMX[4][16];

    int w = threadIdx.x >> 6, lane = threadIdx.x & 63;
    int g = lane >> 4, t = lane & 15;
    int arow = w * 4 + g;
    int slot = blockIdx.x * 16 + arow;  // grid 3125*16 = 50000 exact
    int node = perm[slot];
    if (t == 0) sNode[arow] = node;

    // ---- phase 1: int8 gather-aggregate (16 lanes x 8B per node row), x4 pipelined ----
    {
        int beg = row_ptr[node], end = row_ptr[node + 1];
        float acc[8] = {};
        int e = beg;
        for (; e + 4 <= end; e += 4) {
            int2 a[4];
            uint2 qv[4];
            float sc[4];
#pragma unroll
            for (int j = 0; j < 4; ++j) a[j] = edge2[e + j];
#pragma unroll
            for (int j = 0; j < 4; ++j) {
                qv[j] = qin[a[j].x * 16 + t];
                sc[j] = scin[a[j].x];
            }
#pragma unroll
            for (int j = 0; j < 4; ++j) {
                float ww = __int_as_float(a[j].y) * sc[j];
                uint lo = qv[j].x, hi = qv[j].y;
                acc[0] = fmaf(ww, (float)(char)(lo), acc[0]);
                acc[1] = fmaf(ww, (float)(char)(lo >> 8), acc[1]);
                acc[2] = fmaf(ww, (float)(char)(lo >> 16), acc[2]);
                acc[3] = fmaf(ww, (float)(char)(lo >> 24), acc[3]);
                acc[4] = fmaf(ww, (float)(char)(hi), acc[4]);
                acc[5] = fmaf(ww, (float)(char)(hi >> 8), acc[5]);
                acc[6] = fmaf(ww, (float)(char)(hi >> 16), acc[6]);
                acc[7] = fmaf(ww, (float)(char)(hi >> 24), acc[7]);
            }
        }
        for (; e < end; ++e) {
            int2 a = edge2[e];
            uint2 qv = qin[a.x * 16 + t];
            float ww = __int_as_float(a.y) * scin[a.x];
            uint lo = qv.x, hi = qv.y;
            acc[0] = fmaf(ww, (float)(char)(lo), acc[0]);
            acc[1] = fmaf(ww, (float)(char)(lo >> 8), acc[1]);
            acc[2] = fmaf(ww, (float)(char)(lo >> 16), acc[2]);
            acc[3] = fmaf(ww, (float)(char)(lo >> 24), acc[3]);
            acc[4] = fmaf(ww, (float)(char)(hi), acc[4]);
            acc[5] = fmaf(ww, (float)(char)(hi >> 8), acc[5]);
            acc[6] = fmaf(ww, (float)(char)(hi >> 16), acc[6]);
            acc[7] = fmaf(ww, (float)(char)(hi >> 24), acc[7]);
        }
        {
            float di = dinv[node];
            uint2 qv = qin[node * 16 + t];
            float ww = di * di * scin[node];
            uint lo = qv.x, hi = qv.y;
            acc[0] = fmaf(ww, (float)(char)(lo), acc[0]);
            acc[1] = fmaf(ww, (float)(char)(lo >> 8), acc[1]);
            acc[2] = fmaf(ww, (float)(char)(lo >> 16), acc[2]);
            acc[3] = fmaf(ww, (float)(char)(lo >> 24), acc[3]);
            acc[4] = fmaf(ww, (float)(char)(hi), acc[4]);
            acc[5] = fmaf(ww, (float)(char)(hi >> 8), acc[5]);
            acc[6] = fmaf(ww, (float)(char)(hi >> 16), acc[6]);
            acc[7] = fmaf(ww, (float)(char)(hi >> 24), acc[7]);
        }
        union { ushort us[8]; uint4 u; } pk;
#pragma unroll
        for (int i = 0; i < 8; ++i) pk.us[i] = f2bf_bits(acc[i]);
        sA[arow * 17 + t] = pk.u;
    }
    __syncthreads();

    // ---- phase 2: MFMA 16x128 tile; wave w owns col-tiles 2w, 2w+1 ----
    int q = lane >> 4, m = lane & 15;
    f32x4 c0 = (f32x4){0.f, 0.f, 0.f, 0.f};
    f32x4 c1 = (f32x4){0.f, 0.f, 0.f, 0.f};
    int n0 = 16 * (2 * w), n1 = 16 * (2 * w + 1);
#pragma unroll
    for (int kk = 0; kk < 4; ++kk) {
        bf16x8 af = *(const bf16x8*)&sA[m * 17 + kk * 4 + q];
        bf16x8 b0 = *(const bf16x8*)(Wt + (n0 + m) * DD + kk * 32 + q * 8);
        bf16x8 b1 = *(const bf16x8*)(Wt + (n1 + m) * DD + kk * 32 + q * 8);
        c0 = __builtin_amdgcn_mfma_f32_16x16x32_bf16(af, b0, c0, 0, 0, 0);
        c1 = __builtin_amdgcn_mfma_f32_16x16x32_bf16(af, b1, c1, 0, 0, 0);
    }

    // ---- epilogue: bias + LN + ReLU + residual; non-final layers also emit int8 ----
    float bb0 = bias[n0 + m], bb1 = bias[n1 + m];
    float s1[4], s2[4];
#pragma unroll
    for (int r = 0; r < 4; ++r) {
        float v0 = c0[r] + bb0, v1 = c1[r] + bb1;
        c0[r] = v0; c1[r] = v1;
        s1[r] = v0 + v1;
        s2[r] = v0 * v0 + v1 * v1;
    }
#pragma unroll
    for (int off = 1; off <= 8; off <<= 1) {
#pragma unroll
        for (int r = 0; r < 4; ++r) {
            s1[r] += __shfl_xor(s1[r], off, 64);
            s2[r] += __shfl_xor(s2[r], off, 64);
        }
    }
    if (m == 0) {
#pragma unroll
        for (int r = 0; r < 4; ++r) {
            sLN1[w][q * 4 + r] = s1[r];
            sLN2[w][q * 4 + r] = s2[r];
        }
    }
    __syncthreads();
    float ga0 = gamma[n0 + m], ga1 = gamma[n1 + m];
    float be0 = beta[n0 + m], be1 = beta[n1 + m];
    float o0v[4], o1v[4], rmax[4];
#pragma unroll
    for (int r = 0; r < 4; ++r) {
        int row = q * 4 + r;
        float S1 = sLN1[0][row] + sLN1[1][row] + sLN1[2][row] + sLN1[3][row];
        float S2 = sLN2[0][row] + sLN2[1][row] + sLN2[2][row] + sLN2[3][row];
        float mu = S1 * (1.f / 128.f);
        float var = S2 * (1.f / 128.f) - mu * mu;
        float rstd = rsqrtf(var + LN_EPS);
        int nd = sNode[row];
        size_t rb = (size_t)nd * DD;
        float o0 = fmaxf((c0[r] - mu) * rstd * ga0 + be0, 0.f);
        float o1 = fmaxf((c1[r] - mu) * rstd * ga1 + be1, 0.f);
        if (RES) {
            o0 += __uint_as_float(((uint)fin[rb + n0 + m]) << 16);
            o1 += __uint_as_float(((uint)fin[rb + n1 + m]) << 16);
        }
        if (FINAL) {
            out[rb + n0 + m] = o0;
            out[rb + n1 + m] = o1;
        } else {
            fout[rb + n0 + m] = f2bf_bits(o0);
            fout[rb + n1 + m] = f2bf_bits(o1);
            o0v[r] = o0; o1v[r] = o1;
            rmax[r] = fmaxf(o0, o1);  // o >= 0
        }
    }
    if (!FINAL) {
#pragma unroll
        for (int off = 1; off <= 8; off <<= 1) {
#pragma unroll
            for (int r = 0; r < 4; ++r) rmax[r] = fmaxf(rmax[r], __shfl_xor(rmax[r], off, 64));
        }
        if (m == 0) {
#pragma unroll
            for (int r = 0; r < 4; ++r) sMX[w][q * 4 + r] = rmax[r];
        }
        __syncthreads();
#pragma unroll
        for (int r = 0; r < 4; ++r) {
            int row = q * 4 + r;
            float M = fmaxf(fmaxf(sMX[0][row], sMX[1][row]), fmaxf(sMX[2][row], sMX[3][row]));
            float inv = 127.f / fmaxf(M, 1e-20f);
            int nd = sNode[row];
            if (w == 0 && m == 0) scout[nd] = M / 127.f;
            int q0 = min(__float2int_rn(o0v[r] * inv), 127);
            int q1 = min(__float2int_rn(o1v[r] * inv), 127);
            qfout[(size_t)nd * DD + n0 + m] = (char)q0;
            qfout[(size_t)nd * DD + n1 + m] = (char)q1;
        }
    }
}

// ---------------- launch ----------------

extern "C" void kernel_launch(void* const* d_in, const int* in_sizes, int n_in,
                              void* d_out, int out_size, void* d_ws, size_t ws_size,
                              hipStream_t stream) {
    const float* x = (const float*)d_in[0];
    const int* edge = (const int*)d_in[1];
    const float* Ws = (const float*)d_in[2];
    const float* bs = (const float*)d_in[3];
    const float* gs = (const float*)d_in[4];
    const float* bes = (const float*)d_in[5];
    float* out = (float*)d_out;
    const int* src = edge;
    const int* dst = edge + NE;

    char* p = (char*)d_ws;
    int* counts2 = (int*)p;     p += (size_t)NC2 * 4;     // scanned in place
    int* bsums = (int*)p;       p += 1024 * 4;
    int* row_ptr = (int*)p;     p += (size_t)(NN + 4) * 4;
    int* next_pos2 = (int*)p;   p += (size_t)NC2 * 4;
    float* dinv = (float*)p;    p += (size_t)NN * 4;
    int* degarr = (int*)p;      p += (size_t)NN * 4;
    int* bh = (int*)p;          p += (size_t)PH * 4;
    int* perm = (int*)p;        p += (size_t)NN * 4;
    int2* edge2 = (int2*)p;     p += (size_t)NE * 8;
    ushort* fb0 = (ushort*)p;   p += (size_t)NN * DD * 2;   // bf16 residual chain
    ushort* fb1 = (ushort*)p;   p += (size_t)NN * DD * 2;
    char* qf0 = (char*)p;       p += (size_t)NN * DD;       // int8 gather tables
    char* qf1 = (char*)p;       p += (size_t)NN * DD;
    float* sc0 = (float*)p;     p += (size_t)NN * 4;        // per-row scales
    float* sc1 = (float*)p;     p += (size_t)NN * 4;
    ushort* Wt = (ushort*)p;    p += (size_t)3 * DD * DD * 2;

    hipMemsetAsync(counts2, 0, (size_t)NC2 * 4, stream);
    hist_cast_kernel<<<HHB + QB + WB, 256, 0, stream>>>(src, dst, counts2, x, (uint2*)qf0,
                                                        sc0, Ws, Wt);
    scan1024_blocks<<<NSB, 1024, 0, stream>>>(counts2, bsums);
    scan_sums1024<<<1, 1024, 0, stream>>>(bsums, NSB);
    finalize_kernel<<<NB, 256, 0, stream>>>(counts2, bsums, row_ptr, next_pos2, dinv, degarr,
                                            bh);
    permscan_kernel<<<1, 1024, 0, stream>>>(bh);
    scatter_fill_kernel<<<NB + NSL * 8, 256, 0, stream>>>(degarr, bh, perm, src, dst,
                                                          next_pos2, dinv, edge2);

    int lg = NN / 16;  // 3125
    layer_kernel<false, false><<<lg, 256, 0, stream>>>(
        (const uint2*)qf0, sc0, fb0, row_ptr, edge2, perm, dinv, Wt, bs, gs, bes,
        fb1, qf1, sc1, out);
    layer_kernel<true, false><<<lg, 256, 0, stream>>>(
        (const uint2*)qf1, sc1, fb1, row_ptr, edge2, perm, dinv, Wt + 16384, bs + DD, gs + DD,
        bes + DD, fb0, qf0, sc0, out);
    layer_kernel<true, true><<<lg, 256, 0, stream>>>(
        (const uint2*)qf0, sc0, fb0, row_ptr, edge2, perm, dinv, Wt + 32768, bs + 2 * DD,
        gs + 2 * DD, bes + 2 * DD, fb1, qf1, sc1, out);
}

// Round 14
// 296.688 us; speedup vs baseline: 1.2880x; 1.0151x over previous
//
#include <hip/hip_runtime.h>
#include <hip/hip_bf16.h>

#define NN 50000
#define NE 800000
#define DD 128
#define NB 196             // ceil(NN/256)
#define NCH 8              // source chunks
#define CHSZ 6250          // NN / NCH
#define NC2 (NN * NCH)     // per-(node,chunk) bins = 400000
#define NSB 391            // ceil(NC2/1024)
#define PH (64 * NB)       // degree-bucket histogram size = 12544
#define FS 2048            // edges per slice (hist + fill partitioning)
#define NSL 391            // ceil(NE/FS)
#define HHB (NSL * 8)      // hist blocks, XCD-partitioned = 3128
#define QB 3125            // quant-cast blocks (NN/16)
#define WB 192             // wtcast blocks
#define LN_EPS 1e-5f

typedef __bf16 bf16x8 __attribute__((ext_vector_type(8)));
typedef float f32x4 __attribute__((ext_vector_type(4)));

__device__ inline ushort f2bf_bits(float f) {
    union { __hip_bfloat16 h; ushort u; } c;
    c.h = __float2bfloat16(f);
    return c.u;
}

__device__ inline void accum_q(float* acc, uint2 qv, float ww) {
    uint lo = qv.x, hi = qv.y;
    acc[0] = fmaf(ww, (float)(char)(lo), acc[0]);
    acc[1] = fmaf(ww, (float)(char)(lo >> 8), acc[1]);
    acc[2] = fmaf(ww, (float)(char)(lo >> 16), acc[2]);
    acc[3] = fmaf(ww, (float)(char)(lo >> 24), acc[3]);
    acc[4] = fmaf(ww, (float)(char)(hi), acc[4]);
    acc[5] = fmaf(ww, (float)(char)(hi >> 8), acc[5]);
    acc[6] = fmaf(ww, (float)(char)(hi >> 16), acc[6]);
    acc[7] = fmaf(ww, (float)(char)(hi >> 24), acc[7]);
}

// ---- fused: XCD-partitioned per-(dst,chunk) histogram + int8 row-quant cast + Wt cast ----
__global__ void hist_cast_kernel(const int* __restrict__ src, const int* __restrict__ dst,
                                 int* __restrict__ counts2, const float* __restrict__ x,
                                 uint2* __restrict__ qf0, float* __restrict__ sc0,
                                 const float* __restrict__ W, ushort* __restrict__ Wt) {
    int b = blockIdx.x;
    if (b < HHB) {
        int slice = b >> 3;
        int r = b & 7;
        int base = slice * FS;
#pragma unroll 2
        for (int i = threadIdx.x; i < FS; i += 256) {
            int e = base + i;
            if (e < NE) {
                int d = dst[e];
                if (d / CHSZ == r) {
                    int s = src[e];
                    atomicAdd(&counts2[d * NCH + s / CHSZ], 1);
                }
            }
        }
    } else if (b < HHB + QB) {
        // per-node int8 quantization: 16 lanes x 8 floats = one 128-elem row
        int bb = b - HHB;
        int group = threadIdx.x >> 4, t = threadIdx.x & 15;
        int node = bb * 16 + group;  // 3125*16 = 50000 exact
        const float4* xr = (const float4*)(x + (size_t)node * DD + t * 8);
        float4 v0 = xr[0], v1 = xr[1];
        float vals[8] = {v0.x, v0.y, v0.z, v0.w, v1.x, v1.y, v1.z, v1.w};
        float am = 0.f;
#pragma unroll
        for (int i = 0; i < 8; ++i) am = fmaxf(am, fabsf(vals[i]));
#pragma unroll
        for (int off = 1; off <= 8; off <<= 1) am = fmaxf(am, __shfl_xor(am, off, 64));
        float inv = 127.f / fmaxf(am, 1e-20f);
        uint lo = 0, hi = 0;
#pragma unroll
        for (int i = 0; i < 4; ++i) {
            int q = __float2int_rn(vals[i] * inv);
            lo |= ((uint)(q & 0xff)) << (8 * i);
        }
#pragma unroll
        for (int i = 0; i < 4; ++i) {
            int q = __float2int_rn(vals[4 + i] * inv);
            hi |= ((uint)(q & 0xff)) << (8 * i);
        }
        uint2 pk; pk.x = lo; pk.y = hi;
        qf0[node * 16 + t] = pk;
        if (t == 0) sc0[node] = am / 127.f;
    } else {
        int i = (b - HHB - QB) * 256 + threadIdx.x;  // 3*128*128 = 49152
        int l = i >> 14, k = (i >> 7) & 127, n = i & 127;
        Wt[l * 16384 + n * 128 + k] = f2bf_bits(W[i]);
    }
}

// level-0 scan over NC2 elements, 1024 threads/block, in-place; emits block sums
__global__ __launch_bounds__(1024) void scan1024_blocks(int* __restrict__ data,
                                                        int* __restrict__ bsums) {
    __shared__ int ws[16];
    int gid = blockIdx.x * 1024 + threadIdx.x;
    int lane = threadIdx.x & 63, wid = threadIdx.x >> 6;
    int v = (gid < NC2) ? data[gid] : 0;
    int x = v;
#pragma unroll
    for (int off = 1; off < 64; off <<= 1) {
        int t = __shfl_up(x, off, 64);
        if (lane >= off) x += t;
    }
    if (lane == 63) ws[wid] = x;
    __syncthreads();
    if (threadIdx.x == 0) {
        int run = 0;
        for (int i = 0; i < 16; ++i) { int t = ws[i]; ws[i] = run; run += t; }
        bsums[blockIdx.x] = run;
    }
    __syncthreads();
    if (gid < NC2) data[gid] = x - v + ws[wid];
}

// level-1: single block scans the 391 block sums
__global__ __launch_bounds__(1024) void scan_sums1024(int* __restrict__ bsums, int nb) {
    __shared__ int ws[16];
    int tid = threadIdx.x;
    int lane = tid & 63, wid = tid >> 6;
    int v = (tid < nb) ? bsums[tid] : 0;
    int x = v;
#pragma unroll
    for (int off = 1; off < 64; off <<= 1) {
        int t = __shfl_up(x, off, 64);
        if (lane >= off) x += t;
    }
    if (lane == 63) ws[wid] = x;
    __syncthreads();
    if (tid == 0) {
        int run = 0;
        for (int i = 0; i < 16; ++i) { int t = ws[i]; ws[i] = run; run += t; }
    }
    __syncthreads();
    if (tid < nb) bsums[tid] = x - v + ws[wid];
}

// absolute cursors, row_ptr, degree, dinv + fused per-block degree histogram
__global__ void finalize_kernel(const int* __restrict__ excl2, const int* __restrict__ bsums,
                                int* __restrict__ row_ptr, int* __restrict__ next_pos2,
                                float* __restrict__ dinv, int* __restrict__ degarr,
                                int* __restrict__ bh) {
    __shared__ int lh[64];
    if (threadIdx.x < 64) lh[threadIdx.x] = 0;
    __syncthreads();
    int d = blockIdx.x * 256 + threadIdx.x;
    if (d < NN) {
        int base = d * NCH;
        int p0 = excl2[base] + bsums[base >> 10];
#pragma unroll
        for (int c = 0; c < NCH; ++c) {
            int idx = base + c;
            next_pos2[idx] = excl2[idx] + bsums[idx >> 10];
        }
        int nxt = (d == NN - 1) ? NE : excl2[base + NCH] + bsums[(base + NCH) >> 10];
        int deg = nxt - p0;
        row_ptr[d] = p0;
        dinv[d] = rsqrtf((float)deg + 1.0f);
        degarr[d] = deg;
        atomicAdd(&lh[min(deg, 63)], 1);
    }
    __syncthreads();
    if (threadIdx.x < 64) bh[threadIdx.x * NB + blockIdx.x] = lh[threadIdx.x];
    if (blockIdx.x == 0 && threadIdx.x == 0) row_ptr[NN] = NE;
}

__global__ __launch_bounds__(1024) void permscan_kernel(int* __restrict__ bh) {
    __shared__ int wsum[16];
    const int CH = 13;  // 1024*13 = 13312 >= 12544
    int tid = threadIdx.x;
    int base = tid * CH;
    int vals[CH];
    int s = 0;
#pragma unroll
    for (int i = 0; i < CH; ++i) {
        int idx = base + i;
        int v = (idx < PH) ? bh[idx] : 0;
        vals[i] = s;
        s += v;
    }
    int lane = tid & 63, wid = tid >> 6;
    int x = s;
#pragma unroll
    for (int off = 1; off < 64; off <<= 1) {
        int t = __shfl_up(x, off, 64);
        if (lane >= off) x += t;
    }
    if (lane == 63) wsum[wid] = x;
    __syncthreads();
    if (tid == 0) {
        int run = 0;
        for (int i = 0; i < 16; ++i) { int t = wsum[i]; wsum[i] = run; run += t; }
    }
    __syncthreads();
    int texcl = x - s + wsum[wid];
#pragma unroll
    for (int i = 0; i < CH; ++i) {
        int idx = base + i;
        if (idx < PH) bh[idx] = texcl + vals[i];
    }
}

// merged: blocks [0,NB) = degree-bucket permscatter; blocks [NB, NB+NSL*8) = XCD-
// partitioned fill.
__global__ void scatter_fill_kernel(const int* __restrict__ degarr, const int* __restrict__ bh,
                                    int* __restrict__ perm, const int* __restrict__ src,
                                    const int* __restrict__ dst, int* __restrict__ next_pos2,
                                    const float* __restrict__ dinv, int2* __restrict__ edge2) {
    if (blockIdx.x < NB) {
        __shared__ int lh[64];
        __shared__ int lbase[64];
        if (threadIdx.x < 64) {
            lh[threadIdx.x] = 0;
            lbase[threadIdx.x] = bh[threadIdx.x * NB + blockIdx.x];
        }
        __syncthreads();
        int gid = blockIdx.x * 256 + threadIdx.x;
        if (gid < NN) {
            int b = min(degarr[gid], 63);
            int r = atomicAdd(&lh[b], 1);
            perm[lbase[b] + r] = gid;
        }
    } else {
        int bb = blockIdx.x - NB;
        int slice = bb >> 3;
        int r = bb & 7;
        int base = slice * FS;
#pragma unroll 2
        for (int i = threadIdx.x; i < FS; i += 256) {
            int e = base + i;
            if (e < NE) {
                int d = dst[e];
                if (d / CHSZ == r) {
                    int s = src[e];
                    int pos = atomicAdd(&next_pos2[d * NCH + s / CHSZ], 1);
                    int2 o;
                    o.x = s;
                    o.y = __float_as_int(dinv[s] * dinv[d]);
                    edge2[pos] = o;
                }
            }
        }
    }
}

// ---------------- fused per-layer: int8 gather-aggregate + MFMA GEMM + bias+LN+ReLU+res ----
// int8 table (128B row = 2 lines). R13 evidence: halving FETCH left dur unchanged ->
// latency x concurrency bound, not bandwidth. This round: x8-deep gather pipeline
// (8 edge2 + 8 uint2 gathers + 8 scales in flight; ~60 VGPR, still 8 waves/SIMD).
template <bool RES, bool FINAL>
__global__ __launch_bounds__(256) void layer_kernel(
    const uint2* __restrict__ qin, const float* __restrict__ scin,
    const ushort* __restrict__ fin, const int* __restrict__ row_ptr,
    const int2* __restrict__ edge2, const int* __restrict__ perm,
    const float* __restrict__ dinv, const ushort* __restrict__ Wt,
    const float* __restrict__ bias, const float* __restrict__ gamma,
    const float* __restrict__ beta, ushort* __restrict__ fout, char* __restrict__ qfout,
    float* __restrict__ scout, float* __restrict__ out) {
    __shared__ uint4 sA[16 * 17];
    __shared__ int sNode[16];
    __shared__ float sLN1[4][16], sLN2[4][16];
    __shared__ float sMX[4][16];

    int w = threadIdx.x >> 6, lane = threadIdx.x & 63;
    int g = lane >> 4, t = lane & 15;
    int arow = w * 4 + g;
    int slot = blockIdx.x * 16 + arow;  // grid 3125*16 = 50000 exact
    int node = perm[slot];
    if (t == 0) sNode[arow] = node;

    // ---- phase 1: int8 gather-aggregate (16 lanes x 8B per node row), x8 pipelined ----
    {
        int beg = row_ptr[node], end = row_ptr[node + 1];
        float acc[8] = {};
        int e = beg;
        for (; e + 8 <= end; e += 8) {
            int2 a[8];
            uint2 qv[8];
            float sc[8];
#pragma unroll
            for (int j = 0; j < 8; ++j) a[j] = edge2[e + j];
#pragma unroll
            for (int j = 0; j < 8; ++j) {
                qv[j] = qin[a[j].x * 16 + t];
                sc[j] = scin[a[j].x];
            }
#pragma unroll
            for (int j = 0; j < 8; ++j) accum_q(acc, qv[j], __int_as_float(a[j].y) * sc[j]);
        }
        for (; e + 4 <= end; e += 4) {
            int2 a[4];
            uint2 qv[4];
            float sc[4];
#pragma unroll
            for (int j = 0; j < 4; ++j) a[j] = edge2[e + j];
#pragma unroll
            for (int j = 0; j < 4; ++j) {
                qv[j] = qin[a[j].x * 16 + t];
                sc[j] = scin[a[j].x];
            }
#pragma unroll
            for (int j = 0; j < 4; ++j) accum_q(acc, qv[j], __int_as_float(a[j].y) * sc[j]);
        }
        for (; e < end; ++e) {
            int2 a = edge2[e];
            uint2 qv = qin[a.x * 16 + t];
            accum_q(acc, qv, __int_as_float(a.y) * scin[a.x]);
        }
        {
            float di = dinv[node];
            uint2 qv = qin[node * 16 + t];
            accum_q(acc, qv, di * di * scin[node]);
        }
        union { ushort us[8]; uint4 u; } pk;
#pragma unroll
        for (int i = 0; i < 8; ++i) pk.us[i] = f2bf_bits(acc[i]);
        sA[arow * 17 + t] = pk.u;
    }
    __syncthreads();

    // ---- phase 2: MFMA 16x128 tile; wave w owns col-tiles 2w, 2w+1 ----
    int q = lane >> 4, m = lane & 15;
    f32x4 c0 = (f32x4){0.f, 0.f, 0.f, 0.f};
    f32x4 c1 = (f32x4){0.f, 0.f, 0.f, 0.f};
    int n0 = 16 * (2 * w), n1 = 16 * (2 * w + 1);
#pragma unroll
    for (int kk = 0; kk < 4; ++kk) {
        bf16x8 af = *(const bf16x8*)&sA[m * 17 + kk * 4 + q];
        bf16x8 b0 = *(const bf16x8*)(Wt + (n0 + m) * DD + kk * 32 + q * 8);
        bf16x8 b1 = *(const bf16x8*)(Wt + (n1 + m) * DD + kk * 32 + q * 8);
        c0 = __builtin_amdgcn_mfma_f32_16x16x32_bf16(af, b0, c0, 0, 0, 0);
        c1 = __builtin_amdgcn_mfma_f32_16x16x32_bf16(af, b1, c1, 0, 0, 0);
    }

    // ---- epilogue: bias + LN + ReLU + residual; non-final layers also emit int8 ----
    float bb0 = bias[n0 + m], bb1 = bias[n1 + m];
    float s1[4], s2[4];
#pragma unroll
    for (int r = 0; r < 4; ++r) {
        float v0 = c0[r] + bb0, v1 = c1[r] + bb1;
        c0[r] = v0; c1[r] = v1;
        s1[r] = v0 + v1;
        s2[r] = v0 * v0 + v1 * v1;
    }
#pragma unroll
    for (int off = 1; off <= 8; off <<= 1) {
#pragma unroll
        for (int r = 0; r < 4; ++r) {
            s1[r] += __shfl_xor(s1[r], off, 64);
            s2[r] += __shfl_xor(s2[r], off, 64);
        }
    }
    if (m == 0) {
#pragma unroll
        for (int r = 0; r < 4; ++r) {
            sLN1[w][q * 4 + r] = s1[r];
            sLN2[w][q * 4 + r] = s2[r];
        }
    }
    __syncthreads();
    float ga0 = gamma[n0 + m], ga1 = gamma[n1 + m];
    float be0 = beta[n0 + m], be1 = beta[n1 + m];
    float o0v[4], o1v[4], rmax[4];
#pragma unroll
    for (int r = 0; r < 4; ++r) {
        int row = q * 4 + r;
        float S1 = sLN1[0][row] + sLN1[1][row] + sLN1[2][row] + sLN1[3][row];
        float S2 = sLN2[0][row] + sLN2[1][row] + sLN2[2][row] + sLN2[3][row];
        float mu = S1 * (1.f / 128.f);
        float var = S2 * (1.f / 128.f) - mu * mu;
        float rstd = rsqrtf(var + LN_EPS);
        int nd = sNode[row];
        size_t rb = (size_t)nd * DD;
        float o0 = fmaxf((c0[r] - mu) * rstd * ga0 + be0, 0.f);
        float o1 = fmaxf((c1[r] - mu) * rstd * ga1 + be1, 0.f);
        if (RES) {
            o0 += __uint_as_float(((uint)fin[rb + n0 + m]) << 16);
            o1 += __uint_as_float(((uint)fin[rb + n1 + m]) << 16);
        }
        if (FINAL) {
            out[rb + n0 + m] = o0;
            out[rb + n1 + m] = o1;
        } else {
            fout[rb + n0 + m] = f2bf_bits(o0);
            fout[rb + n1 + m] = f2bf_bits(o1);
            o0v[r] = o0; o1v[r] = o1;
            rmax[r] = fmaxf(o0, o1);  // o >= 0
        }
    }
    if (!FINAL) {
#pragma unroll
        for (int off = 1; off <= 8; off <<= 1) {
#pragma unroll
            for (int r = 0; r < 4; ++r) rmax[r] = fmaxf(rmax[r], __shfl_xor(rmax[r], off, 64));
        }
        if (m == 0) {
#pragma unroll
            for (int r = 0; r < 4; ++r) sMX[w][q * 4 + r] = rmax[r];
        }
        __syncthreads();
#pragma unroll
        for (int r = 0; r < 4; ++r) {
            int row = q * 4 + r;
            float M = fmaxf(fmaxf(sMX[0][row], sMX[1][row]), fmaxf(sMX[2][row], sMX[3][row]));
            float inv = 127.f / fmaxf(M, 1e-20f);
            int nd = sNode[row];
            if (w == 0 && m == 0) scout[nd] = M / 127.f;
            int q0 = min(__float2int_rn(o0v[r] * inv), 127);
            int q1 = min(__float2int_rn(o1v[r] * inv), 127);
            qfout[(size_t)nd * DD + n0 + m] = (char)q0;
            qfout[(size_t)nd * DD + n1 + m] = (char)q1;
        }
    }
}

// ---------------- launch ----------------

extern "C" void kernel_launch(void* const* d_in, const int* in_sizes, int n_in,
                              void* d_out, int out_size, void* d_ws, size_t ws_size,
                              hipStream_t stream) {
    const float* x = (const float*)d_in[0];
    const int* edge = (const int*)d_in[1];
    const float* Ws = (const float*)d_in[2];
    const float* bs = (const float*)d_in[3];
    const float* gs = (const float*)d_in[4];
    const float* bes = (const float*)d_in[5];
    float* out = (float*)d_out;
    const int* src = edge;
    const int* dst = edge + NE;

    char* p = (char*)d_ws;
    int* counts2 = (int*)p;     p += (size_t)NC2 * 4;     // scanned in place
    int* bsums = (int*)p;       p += 1024 * 4;
    int* row_ptr = (int*)p;     p += (size_t)(NN + 4) * 4;
    int* next_pos2 = (int*)p;   p += (size_t)NC2 * 4;
    float* dinv = (float*)p;    p += (size_t)NN * 4;
    int* degarr = (int*)p;      p += (size_t)NN * 4;
    int* bh = (int*)p;          p += (size_t)PH * 4;
    int* perm = (int*)p;        p += (size_t)NN * 4;
    int2* edge2 = (int2*)p;     p += (size_t)NE * 8;
    ushort* fb0 = (ushort*)p;   p += (size_t)NN * DD * 2;   // bf16 residual chain
    ushort* fb1 = (ushort*)p;   p += (size_t)NN * DD * 2;
    char* qf0 = (char*)p;       p += (size_t)NN * DD;       // int8 gather tables
    char* qf1 = (char*)p;       p += (size_t)NN * DD;
    float* sc0 = (float*)p;     p += (size_t)NN * 4;        // per-row scales
    float* sc1 = (float*)p;     p += (size_t)NN * 4;
    ushort* Wt = (ushort*)p;    p += (size_t)3 * DD * DD * 2;

    hipMemsetAsync(counts2, 0, (size_t)NC2 * 4, stream);
    hist_cast_kernel<<<HHB + QB + WB, 256, 0, stream>>>(src, dst, counts2, x, (uint2*)qf0,
                                                        sc0, Ws, Wt);
    scan1024_blocks<<<NSB, 1024, 0, stream>>>(counts2, bsums);
    scan_sums1024<<<1, 1024, 0, stream>>>(bsums, NSB);
    finalize_kernel<<<NB, 256, 0, stream>>>(counts2, bsums, row_ptr, next_pos2, dinv, degarr,
                                            bh);
    permscan_kernel<<<1, 1024, 0, stream>>>(bh);
    scatter_fill_kernel<<<NB + NSL * 8, 256, 0, stream>>>(degarr, bh, perm, src, dst,
                                                          next_pos2, dinv, edge2);

    int lg = NN / 16;  // 3125
    layer_kernel<false, false><<<lg, 256, 0, stream>>>(
        (const uint2*)qf0, sc0, fb0, row_ptr, edge2, perm, dinv, Wt, bs, gs, bes,
        fb1, qf1, sc1, out);
    layer_kernel<true, false><<<lg, 256, 0, stream>>>(
        (const uint2*)qf1, sc1, fb1, row_ptr, edge2, perm, dinv, Wt + 16384, bs + DD, gs + DD,
        bes + DD, fb0, qf0, sc0, out);
    layer_kernel<true, true><<<lg, 256, 0, stream>>>(
        (const uint2*)qf0, sc0, fb0, row_ptr, edge2, perm, dinv, Wt + 32768, bs + 2 * DD,
        gs + 2 * DD, bes + 2 * DD, fb1, qf1, sc1, out);
}